// Round 12
// baseline (811.096 us; speedup 1.0000x reference)
//
#include <hip/hip_runtime.h>
#include <math.h>

#define M_REAL 13320
#define M_PAD  13440          // 105 * 128
#define B_BATCH 240
#define LN_EPS 1e-5f

#define MS512  ((size_t)M_PAD * 512)
#define MS2048 ((size_t)M_PAD * 2048)

typedef __attribute__((ext_vector_type(8))) short short8;   // bf16x8 frag (4 VGPR)
typedef __attribute__((ext_vector_type(4))) float f32x4;    // MFMA acc

__device__ __forceinline__ ushort f2bf(float f) {
    unsigned u = __float_as_uint(f);
    u += 0x7FFFu + ((u >> 16) & 1u);           // RNE
    return (ushort)(u >> 16);
}
__device__ __forceinline__ float bf2f(ushort h) {
    return __uint_as_float(((unsigned)h) << 16);
}
__device__ __forceinline__ int sel4(int4 v, int z) {
    return z == 0 ? v.x : z == 1 ? v.y : z == 2 ? v.z : v.w;
}

typedef __attribute__((address_space(3))) unsigned int lds_u32;
typedef __attribute__((address_space(1))) unsigned int glb_u32;
__device__ __forceinline__ void gl_lds16(const ushort* g, ushort* l) {
    __builtin_amdgcn_global_load_lds((glb_u32*)g, (lds_u32*)l, 16, 0, 0);
}

// ---------------- offsets ----------------
__global__ void k_offsets(const int* __restrict__ num_objs, int* __restrict__ offs) {
    if (threadIdx.x == 0) {
        int acc = 0;
        for (int b = 0; b < B_BATCH; ++b) { offs[b] = acc; acc += num_objs[b]; }
    }
}

// ---------------- f32 [M_REAL,512] -> bf16 [M_PAD,512], zero pad rows -------
__global__ __launch_bounds__(256)
void k_cvt_in(const float* __restrict__ src, ushort* __restrict__ dst) {
    int idx = blockIdx.x * 256 + threadIdx.x;   // one thread = 8 elems
    int row = idx >> 6;
    short8 o;
    if (row < M_REAL) {
        const float4* s = (const float4*)src + (size_t)idx * 2;
        float4 a = s[0], b = s[1];
        o[0] = (short)f2bf(a.x); o[1] = (short)f2bf(a.y);
        o[2] = (short)f2bf(a.z); o[3] = (short)f2bf(a.w);
        o[4] = (short)f2bf(b.x); o[5] = (short)f2bf(b.y);
        o[6] = (short)f2bf(b.z); o[7] = (short)f2bf(b.w);
    } else {
        o = (short8)0;
    }
    ((short8*)dst)[idx] = o;
}

// ---------------- bias concat: bqkv[e][1536] = cat(bq,bk,bv) -----------------
__global__ void k_cat_bias(const float* __restrict__ bq, const float* __restrict__ bk,
                           const float* __restrict__ bv, float* __restrict__ out) {
    int idx = blockIdx.x * 256 + threadIdx.x;
    if (idx >= 4 * 1536) return;
    int e = idx / 1536, c = idx - e * 1536;
    float v = (c < 512) ? bq[e * 512 + c] : (c < 1024) ? bk[e * 512 + c - 512]
                                                       : bv[e * 512 + c - 1024];
    out[idx] = v;
}

// ---------------- weight transpose+cvt: f32 [R,C] -> bf16 [C,R] --------------
__global__ __launch_bounds__(256)
void k_wt(const float* __restrict__ src, ushort* __restrict__ dst, int R, int C,
          size_t dstStride, size_t dstOff) {
    __shared__ float t[32][33];
    const float* s = src + (size_t)blockIdx.z * R * C;
    ushort* d = dst + (size_t)blockIdx.z * dstStride + dstOff;
    int tx = threadIdx.x & 31, ty = threadIdx.x >> 5;   // 32 x 8
    int r0 = blockIdx.y * 32, c0 = blockIdx.x * 32;
#pragma unroll
    for (int i = 0; i < 4; ++i)
        t[ty + i * 8][tx] = s[(size_t)(r0 + ty + i * 8) * C + c0 + tx];
    __syncthreads();
#pragma unroll
    for (int i = 0; i < 4; ++i)
        d[(size_t)(c0 + ty + i * 8) * R + r0 + tx] = f2bf(t[tx][ty + i * 8]);
}

// ---------------- bf16 MFMA GEMM: 32KB LDS (single-stage) + coalesced epi ----
// r9's kernel with LDS halved for occupancy: single 16KB+16KB staging buffer
// (r5's proven protocol: stage -> barrier -> compute -> barrier) and the
// coalesced LDS-bounce epilogue split into two 32KB half-passes (Cs[64][128]).
// LDS 32KB/block -> up to 5 blocks/CU (regs ~3): cross-block wave overlap
// (m114) hides the per-block staging latency the dbuf protocols couldn't.
enum { EPI_BF16 = 0, EPI_BF16_RELU = 1, EPI_F32_RESF32 = 2, EPI_F32_RESBF16 = 3 };

template<int MODE>
__global__ __launch_bounds__(256)
void k_gemm16(const ushort* __restrict__ A, const ushort* __restrict__ A2, int bySplit,
              size_t zA, int lda,
              const ushort* __restrict__ Wb, size_t wSize, int4 widx, int K,
              const float* __restrict__ biasB, int biasStride,
              const void* __restrict__ resv, const void* __restrict__ resv2,
              int resSplit, size_t zRes,
              void* __restrict__ Cv, size_t zC, int ldc, int Mreal) {
    __shared__ __attribute__((aligned(16))) char smem[32768];
    ushort* As = (ushort*)smem;                    // 16KB
    ushort* Bs = (ushort*)(smem + 16384);          // 16KB
    float*  Cs = (float*)smem;                     // [64][128] f32 (epilogue halves)
    const int tid = threadIdx.x;

    // ---- XCD-chunked remap: dispatch ordinal d -> contiguous work per XCD ----
    const int NX = gridDim.x, NY = gridDim.y;
    const int NB = NX * NY * (int)gridDim.z;
    int d = blockIdx.x + NX * (blockIdx.y + NY * blockIdx.z);
    int qq = NB >> 3, rr = NB & 7;
    int xcd = d & 7, idx = d >> 3;
    int work = (xcd < rr ? xcd * (qq + 1) : rr * (qq + 1) + (xcd - rr) * qq) + idx;
    const int z = work / (NX * NY);
    int rem = work - z * (NX * NY);
    const int panel = rem / NY;            // row-panel index (col-fastest within panel)
    const int colb = rem - panel * NY;
    const int row0 = panel * 128;
    const int col0 = colb * 128;

    const ushort* Ause = ((colb < bySplit) ? A : A2) + (size_t)z * zA;
    const ushort* Wt = Wb + (size_t)sel4(widx, z) * wSize;
    const float* bias = biasB + (size_t)sel4(widx, z) * biasStride;
    const int zi = (z < resSplit) ? z : z - resSplit;
    const float*  resF = (const float*)((z < resSplit) ? resv : resv2) + (size_t)zi * zRes;
    const ushort* resH = (const ushort*)((z < resSplit) ? resv : resv2) + (size_t)zi * zRes;
    ushort* C16 = (ushort*)Cv + (size_t)z * zC;
    float*  C32 = (float*)Cv + (size_t)z * zC;

    const int lane = tid & 63, wid = tid >> 6;
    const int wr = wid >> 1, wc = wid & 1;
    const int fr = lane & 15, fq = lane >> 4;

    int srow[4], scol[4], soff[4];
#pragma unroll
    for (int r = 0; r < 4; ++r) {
        int off = tid * 16 + r * 4096;
        int row = off >> 7;
        int cp  = (off >> 4) & 7;
        soff[r] = off;
        srow[r] = row;
        scol[r] = (cp ^ (row & 7)) * 8;
    }

    f32x4 acc[4][4];
#pragma unroll
    for (int m = 0; m < 4; ++m)
#pragma unroll
        for (int n = 0; n < 4; ++n) acc[m][n] = (f32x4){0.f, 0.f, 0.f, 0.f};

    const int nk = K >> 6;

    for (int kt = 0; kt < nk; ++kt) {
        const int k0 = kt << 6;
#pragma unroll
        for (int r = 0; r < 4; ++r)
            gl_lds16(Ause + (size_t)(row0 + srow[r]) * lda + k0 + scol[r],
                     (ushort*)((char*)As + soff[r]));
#pragma unroll
        for (int r = 0; r < 4; ++r)
            gl_lds16(Wt + (size_t)(col0 + srow[r]) * K + k0 + scol[r],
                     (ushort*)((char*)Bs + soff[r]));
        __syncthreads();   // compiler drains vmcnt(0): staged tile visible
#pragma unroll
        for (int kk = 0; kk < 2; ++kk) {
            short8 av[4], bv[4];
#pragma unroll
            for (int m = 0; m < 4; ++m) {
                int row = wr * 64 + m * 16 + fr;
                int byte = row * 128 + (((kk * 4 + fq) ^ (row & 7)) << 4);
                av[m] = *(const short8*)((const char*)As + byte);
            }
#pragma unroll
            for (int n = 0; n < 4; ++n) {
                int row = wc * 64 + n * 16 + fr;
                int byte = row * 128 + (((kk * 4 + fq) ^ (row & 7)) << 4);
                bv[n] = *(const short8*)((const char*)Bs + byte);
            }
#pragma unroll
            for (int m = 0; m < 4; ++m)
#pragma unroll
                for (int n = 0; n < 4; ++n)
                    acc[m][n] = __builtin_amdgcn_mfma_f32_16x16x32_bf16(av[m], bv[n], acc[m][n], 0, 0, 0);
        }
        __syncthreads();   // WAR: all reads done before next stage / epilogue Cs
    }

    // ---- epilogue: coalesced stores via Cs[64][128] f32, two half-passes ----
    const int tr = tid >> 4, tc = tid & 15;
    float bias8[8];
#pragma unroll
    for (int j = 0; j < 8; ++j) bias8[j] = bias[col0 + tc * 8 + j];
#pragma unroll
    for (int half = 0; half < 2; ++half) {
        if (wr == half) {
#pragma unroll
            for (int m = 0; m < 4; ++m)
#pragma unroll
                for (int n = 0; n < 4; ++n) {
                    int r = m * 16 + fq * 4;               // row within half
                    int c = wc * 64 + n * 16 + fr;
#pragma unroll
                    for (int i = 0; i < 4; ++i)
                        Cs[(r + i) * 128 + c] = acc[m][n][i];
                }
        }
        __syncthreads();
#pragma unroll
        for (int g = 0; g < 4; ++g) {
            int r = g * 16 + tr;
            int gr = row0 + half * 64 + r;
            size_t obase = (size_t)gr * ldc + col0 + tc * 8;
            const float* crow = &Cs[r * 128 + tc * 8];
            float v[8];
            *(float4*)&v[0] = *(const float4*)&crow[0];
            *(float4*)&v[4] = *(const float4*)&crow[4];
#pragma unroll
            for (int j = 0; j < 8; ++j) v[j] += bias8[j];
            if (MODE == EPI_BF16 || MODE == EPI_BF16_RELU) {
                short8 o;
#pragma unroll
                for (int j = 0; j < 8; ++j) {
                    float x = (MODE == EPI_BF16_RELU) ? fmaxf(v[j], 0.f) : v[j];
                    o[j] = (short)f2bf(x);
                }
                *(short8*)&C16[obase] = o;
            } else if (MODE == EPI_F32_RESF32) {
                if (gr < Mreal) {
                    float4 r0 = *(const float4*)&resF[obase];
                    float4 r1 = *(const float4*)&resF[obase + 4];
                    v[0] += r0.x; v[1] += r0.y; v[2] += r0.z; v[3] += r0.w;
                    v[4] += r1.x; v[5] += r1.y; v[6] += r1.z; v[7] += r1.w;
                }
                *(float4*)&C32[obase] = *(float4*)&v[0];
                *(float4*)&C32[obase + 4] = *(float4*)&v[4];
            } else {
                short8 rh = *(const short8*)&resH[obase];
#pragma unroll
                for (int j = 0; j < 8; ++j) v[j] += bf2f((ushort)rh[j]);
                *(float4*)&C32[obase] = *(float4*)&v[0];
                *(float4*)&C32[obase + 4] = *(float4*)&v[4];
            }
        }
        if (half == 0) __syncthreads();
    }
}

// ---------------- MFMA segment attention (verified) --------------------------
#define KS_STRIDE 72
#define VT_STRIDE 104
#define PL_STRIDE 104

__global__ __launch_bounds__(256)
void k_attn_mfma(const ushort* __restrict__ QKV, const int* __restrict__ offs,
                 const int* __restrict__ num_objs, ushort* __restrict__ CTX) {
    __shared__ __attribute__((aligned(16))) ushort Ks[96 * KS_STRIDE];
    __shared__ __attribute__((aligned(16))) ushort Vt[64 * VT_STRIDE];
    __shared__ __attribute__((aligned(16))) ushort Pl[64 * PL_STRIDE];
    const int b = blockIdx.x, h = blockIdx.y;
    const int L = num_objs[b], off = offs[b];
    const int tid = threadIdx.x;
    const int lane = tid & 63, wid = tid >> 6;
    const int fr = lane & 15, fq = lane >> 4;

#pragma unroll
    for (int pass = 0; pass < 3; ++pass) {
        int j = pass * 32 + (tid >> 3);
        int d0 = (tid & 7) * 8;
        short8 kv = (short8)0, vv = (short8)0;
        if (j < L) {
            size_t base = (size_t)(off + j) * 1536 + h * 64 + d0;
            kv = *(const short8*)(QKV + base + 512);
            vv = *(const short8*)(QKV + base + 1024);
        }
        *(short8*)&Ks[j * KS_STRIDE + d0] = kv;
#pragma unroll
        for (int e = 0; e < 8; ++e) Vt[(d0 + e) * VT_STRIDE + j] = (ushort)vv[e];
    }
    __syncthreads();

    const int nkb = (L + 15) >> 4;
    const int nkc = (nkb + 1) >> 1;

    for (int qb = wid; qb < 6; qb += 4) {
        if (qb >= nkb) continue;
        const int q0 = qb * 16;
        const int qrow = q0 + fr;
        const int qc = (qrow < L) ? qrow : (L - 1);
        const ushort* qbase = QKV + (size_t)(off + qc) * 1536 + h * 64 + fq * 8;
        short8 qf0 = *(const short8*)qbase;
        short8 qf1 = *(const short8*)(qbase + 32);

        f32x4 st[6];
#pragma unroll 6
        for (int kb = 0; kb < nkb; ++kb) {
            short8 a0 = *(const short8*)&Ks[(kb * 16 + fr) * KS_STRIDE + fq * 8];
            short8 a1 = *(const short8*)&Ks[(kb * 16 + fr) * KS_STRIDE + 32 + fq * 8];
            f32x4 acc = (f32x4){0.f, 0.f, 0.f, 0.f};
            acc = __builtin_amdgcn_mfma_f32_16x16x32_bf16(a0, qf0, acc, 0, 0, 0);
            acc = __builtin_amdgcn_mfma_f32_16x16x32_bf16(a1, qf1, acc, 0, 0, 0);
            st[kb] = acc;
        }

        float m = -1e30f;
#pragma unroll 6
        for (int kb = 0; kb < nkb; ++kb)
#pragma unroll
            for (int i = 0; i < 4; ++i) {
                int k = kb * 16 + fq * 4 + i;
                if (k < L) m = fmaxf(m, st[kb][i] * 0.125f);
            }
        m = fmaxf(m, __shfl_xor(m, 16));
        m = fmaxf(m, __shfl_xor(m, 32));
        float sum = 0.f;
        float pv[6][4];
#pragma unroll
        for (int kb = 0; kb < 6; ++kb)
#pragma unroll
            for (int i = 0; i < 4; ++i) {
                float p = 0.f;
                if (kb < nkb) {
                    int k = kb * 16 + fq * 4 + i;
                    if (k < L) p = __expf(st[kb][i] * 0.125f - m);
                }
                pv[kb][i] = p;
                sum += p;
            }
        sum += __shfl_xor(sum, 16);
        sum += __shfl_xor(sum, 32);
        float inv = 1.f / sum;

        ushort* prow = &Pl[(wid * 16 + fr) * PL_STRIDE];
#pragma unroll
        for (int kb = 0; kb < 6; ++kb) {
            unsigned lo = (unsigned)f2bf(pv[kb][0]) | ((unsigned)f2bf(pv[kb][1]) << 16);
            unsigned hi = (unsigned)f2bf(pv[kb][2]) | ((unsigned)f2bf(pv[kb][3]) << 16);
            *(unsigned*)&prow[kb * 16 + fq * 4]     = lo;
            *(unsigned*)&prow[kb * 16 + fq * 4 + 2] = hi;
        }

        f32x4 ct[4];
#pragma unroll
        for (int db = 0; db < 4; ++db) ct[db] = (f32x4){0.f, 0.f, 0.f, 0.f};
        const ushort* prd = &Pl[(wid * 16 + fr) * PL_STRIDE];
#pragma unroll 3
        for (int kc = 0; kc < nkc; ++kc) {
            short8 pf = *(const short8*)&prd[kc * 32 + fq * 8];
#pragma unroll
            for (int db = 0; db < 4; ++db) {
                short8 vf = *(const short8*)&Vt[(db * 16 + fr) * VT_STRIDE + kc * 32 + fq * 8];
                ct[db] = __builtin_amdgcn_mfma_f32_16x16x32_bf16(vf, pf, ct[db], 0, 0, 0);
            }
        }

        if (qrow < L) {
            ushort* crow = CTX + (size_t)(off + qrow) * 512 + h * 64;
#pragma unroll
            for (int db = 0; db < 4; ++db) {
                ushort4 o;
                o.x = f2bf(ct[db][0] * inv);
                o.y = f2bf(ct[db][1] * inv);
                o.z = f2bf(ct[db][2] * inv);
                o.w = f2bf(ct[db][3] * inv);
                *(ushort4*)&crow[db * 16 + fq * 4] = o;
            }
        }
    }
}

// ---------------- LayerNorm helpers (one wave per row) -----------------------
__device__ __forceinline__ void ln_row8(const float* __restrict__ X, const float* __restrict__ g,
                                        const float* __restrict__ be, int lane, float* o) {
    const float4* x4 = (const float4*)X;
    float4 v0 = x4[2 * lane], v1 = x4[2 * lane + 1];
    float s = v0.x + v0.y + v0.z + v0.w + v1.x + v1.y + v1.z + v1.w;
    for (int t = 32; t > 0; t >>= 1) s += __shfl_xor(s, t);
    float mean = s * (1.f / 512.f);
    float dd[8] = {v0.x - mean, v0.y - mean, v0.z - mean, v0.w - mean,
                   v1.x - mean, v1.y - mean, v1.z - mean, v1.w - mean};
    float vs = 0.f;
#pragma unroll
    for (int i = 0; i < 8; ++i) vs += dd[i] * dd[i];
    for (int t = 32; t > 0; t >>= 1) vs += __shfl_xor(vs, t);
    float rstd = rsqrtf(vs * (1.f / 512.f) + LN_EPS);
    const float4* g4 = (const float4*)g;
    const float4* b4 = (const float4*)be;
    float4 ga = g4[2 * lane], gb = g4[2 * lane + 1];
    float4 ba = b4[2 * lane], bb = b4[2 * lane + 1];
    o[0] = dd[0] * rstd * ga.x + ba.x;  o[1] = dd[1] * rstd * ga.y + ba.y;
    o[2] = dd[2] * rstd * ga.z + ba.z;  o[3] = dd[3] * rstd * ga.w + ba.w;
    o[4] = dd[4] * rstd * gb.x + bb.x;  o[5] = dd[5] * rstd * gb.y + bb.y;
    o[6] = dd[6] * rstd * gb.z + bb.z;  o[7] = dd[7] * rstd * gb.w + bb.w;
}

// LN1 batched over z encoders (z=blockIdx.y), bf16 out. 4 rows per block.
__global__ __launch_bounds__(256)
void k_ln1(const float* __restrict__ Xb, const float* __restrict__ gB,
           const float* __restrict__ beB, ushort* __restrict__ outB, int4 widx) {
    int e = blockIdx.y;
    int row = blockIdx.x * 4 + (threadIdx.x >> 6);
    int lane = threadIdx.x & 63;
    int pi = sel4(widx, e);
    float o[8];
    ln_row8(Xb + (size_t)e * MS512 + (size_t)row * 512, gB + pi * 512, beB + pi * 512, lane, o);
    short8 o8;
#pragma unroll
    for (int i = 0; i < 8; ++i) o8[i] = (short)f2bf(o[i]);
    ((short8*)(outB + (size_t)e * MS512 + (size_t)row * 512))[lane] = o8;
}

// LN2 + pair sum: dst = LN(Ob2[0]; pA) + LN(Ob2[1]; pB)
__global__ __launch_bounds__(256)
void k_ln2pair(const float* __restrict__ Ob2, const float* __restrict__ gB,
               const float* __restrict__ beB, float* __restrict__ dst,
               int pA, int pB) {
    int row = blockIdx.x * 4 + (threadIdx.x >> 6);
    int lane = threadIdx.x & 63;
    float oA[8], oB[8];
    ln_row8(Ob2 + (size_t)row * 512,         gB + pA * 512, beB + pA * 512, lane, oA);
    ln_row8(Ob2 + MS512 + (size_t)row * 512, gB + pB * 512, beB + pB * 512, lane, oB);
    if (row < M_REAL) {
        float* drow = dst + (size_t)row * 512;
        float4 s0, s1;
        s0.x = oA[0] + oB[0]; s0.y = oA[1] + oB[1]; s0.z = oA[2] + oB[2]; s0.w = oA[3] + oB[3];
        s1.x = oA[4] + oB[4]; s1.y = oA[5] + oB[5]; s1.z = oA[6] + oB[6]; s1.w = oA[7] + oB[7];
        ((float4*)drow)[2 * lane] = s0;
        ((float4*)drow)[2 * lane + 1] = s1;
    }
}

// ---------------- driver ------------------------------------------------------
extern "C" void kernel_launch(void* const* d_in, const int* in_sizes, int n_in,
                              void* d_out, int out_size, void* d_ws, size_t ws_size,
                              hipStream_t stream) {
    const float* vis = (const float*)d_in[0];
    const float* txt = (const float*)d_in[1];
    const float* Wq  = (const float*)d_in[2];
    const float* bq  = (const float*)d_in[3];
    const float* Wk  = (const float*)d_in[4];
    const float* bk  = (const float*)d_in[5];
    const float* Wv  = (const float*)d_in[6];
    const float* bv  = (const float*)d_in[7];
    const float* Wo  = (const float*)d_in[8];
    const float* bo  = (const float*)d_in[9];
    const float* g1  = (const float*)d_in[10];
    const float* be1 = (const float*)d_in[11];
    const float* W1  = (const float*)d_in[12];
    const float* b1  = (const float*)d_in[13];
    const float* W2  = (const float*)d_in[14];
    const float* b2  = (const float*)d_in[15];
    const float* g2  = (const float*)d_in[16];
    const float* be2 = (const float*)d_in[17];
    const int* num_objs = (const int*)d_in[18];

    // ---- workspace (aliased unions): 190.3 MB total ----
    char* p = (char*)d_ws;
    ushort* QKV16  = (ushort*)p;               // U1: [M_PAD][1536] bf16 (QKV phase)
    ushort* H16    = (ushort*)p;               // U1: [M_PAD][2048] bf16 (FFN phase)
    p += (size_t)M_PAD * 2048 * 2;
    ushort* CTX2   = (ushort*)p;               // U2: [2][M_PAD][512] bf16 (attn out)
    ushort* O116_2 = (ushort*)p;               // U2 alias: LN1 out (CTX dead after Wo)
    p += (size_t)2 * MS512 * 2;
    float*  Ob2    = (float*)p;                // U3: [2][M_PAD][512] f32
    p += (size_t)2 * MS512 * 4;
    ushort* vis16  = (ushort*)p;  p += MS512 * 2;
    ushort* txt16  = (ushort*)p;  p += MS512 * 2;
    ushort* wqkv16 = (ushort*)p;  p += (size_t)4 * 1536 * 512 * 2;
    ushort* wo16   = (ushort*)p;  p += (size_t)4 * 512 * 512 * 2;
    ushort* w116   = (ushort*)p;  p += (size_t)4 * 2048 * 512 * 2;
    ushort* w216   = (ushort*)p;  p += (size_t)4 * 512 * 2048 * 2;
    float*  bqkv   = (float*)p;   p += (size_t)4 * 1536 * 4;
    int*    offs   = (int*)p;     p += 1024;

    float* outv = (float*)d_out;
    float* outt = outv + (size_t)M_REAL * 512;

    k_offsets<<<1, 64, 0, stream>>>(num_objs, offs);
    k_cvt_in<<<3360, 256, 0, stream>>>(vis, vis16);
    k_cvt_in<<<3360, 256, 0, stream>>>(txt, txt16);
    k_cat_bias<<<24, 256, 0, stream>>>(bq, bk, bv, bqkv);
    // wqkv[e] = [1536][512]: rows 0-511 Wq^T, 512-1023 Wk^T, 1024-1535 Wv^T
    k_wt<<<dim3(16, 16, 4), 256, 0, stream>>>(Wq, wqkv16, 512, 512, (size_t)1536 * 512, 0);
    k_wt<<<dim3(16, 16, 4), 256, 0, stream>>>(Wk, wqkv16, 512, 512, (size_t)1536 * 512, (size_t)512 * 512);
    k_wt<<<dim3(16, 16, 4), 256, 0, stream>>>(Wv, wqkv16, 512, 512, (size_t)1536 * 512, (size_t)1024 * 512);
    k_wt<<<dim3(16, 16, 4), 256, 0, stream>>>(Wo, wo16, 512, 512, (size_t)512 * 512, 0);
    k_wt<<<dim3(64, 16, 4), 256, 0, stream>>>(W1, w116, 512, 2048, (size_t)2048 * 512, 0);
    k_wt<<<dim3(16, 64, 4), 256, 0, stream>>>(W2, w216, 2048, 512, (size_t)512 * 2048, 0);

    // e order: 0=tsa(txt,txt,p1) 1=tca(txt,vis,p3) 2=vsa(vis,vis,p0) 3=vca(vis,txt,p2)
    const int perm[4] = {1, 3, 0, 2};
    const ushort* qsrc[4]  = {txt16, txt16, vis16, vis16};
    const ushort* kvsrc[4] = {txt16, vis16, vis16, txt16};

    for (int pr = 0; pr < 2; ++pr) {
        // ---- QKV (fused N=1536) + attention, per encoder of the pair ----
        for (int z = 0; z < 2; ++z) {
            int e = 2 * pr + z;
            int4 wz = make_int4(perm[e], perm[e], perm[e], perm[e]);
            k_gemm16<EPI_BF16><<<dim3(105, 12, 1), 256, 0, stream>>>(
                qsrc[e], kvsrc[e], 4, 0, 512,
                wqkv16, (size_t)1536 * 512, wz, 512,
                bqkv, 1536,
                nullptr, nullptr, 8, 0,
                QKV16, 0, 1536, M_PAD);
            k_attn_mfma<<<dim3(B_BATCH, 8), 256, 0, stream>>>(
                QKV16, offs, num_objs, CTX2 + (size_t)z * MS512);
        }
        // ---- Wo (z=2): Ob2[z] = CTX2[z]@Wo + bo + q_in (f32) ----
        int4 wzp = make_int4(perm[2 * pr], perm[2 * pr + 1], 0, 0);
        const float* resq = pr ? vis : txt;
        k_gemm16<EPI_F32_RESF32><<<dim3(105, 4, 2), 256, 0, stream>>>(
            CTX2, CTX2, 99, MS512, 512,
            wo16, (size_t)512 * 512, wzp, 512,
            bo, 512,
            resq, resq, 2, 0,
            Ob2, MS512, 512, M_REAL);
        // ---- LN1 (z=2) -> bf16 (overwrites CTX alias) ----
        k_ln1<<<dim3(3360, 2), 256, 0, stream>>>(Ob2, g1, be1, O116_2, wzp);
        // ---- FFN per encoder (H16 single-buffer) ----
        for (int z = 0; z < 2; ++z) {
            int e = 2 * pr + z;
            int4 wz = make_int4(perm[e], perm[e], perm[e], perm[e]);
            k_gemm16<EPI_BF16_RELU><<<dim3(105, 16, 1), 256, 0, stream>>>(
                O116_2 + (size_t)z * MS512, O116_2, 99, 0, 512,
                w116, (size_t)2048 * 512, wz, 512,
                b1, 2048,
                nullptr, nullptr, 8, 0,
                H16, 0, 2048, M_PAD);
            k_gemm16<EPI_F32_RESBF16><<<dim3(105, 4, 1), 256, 0, stream>>>(
                H16, H16, 99, 0, 2048,
                w216, (size_t)512 * 2048, wz, 2048,
                b2, 512,
                O116_2 + (size_t)z * MS512, nullptr, 8, 0,
                Ob2 + (size_t)z * MS512, 0, 512, M_PAD);
        }
        // ---- LN2 + pair sum -> output ----
        k_ln2pair<<<3360, 256, 0, stream>>>(Ob2, g2, be2, pr ? outv : outt,
                                            pr ? 0 : 1, pr ? 2 : 3);
    }
}

// Round 13
// 731.374 us; speedup vs baseline: 1.1090x; 1.1090x over previous
//
#include <hip/hip_runtime.h>
#include <math.h>

#define M_REAL 13320
#define M_PAD  13440          // 105 * 128
#define B_BATCH 240
#define LN_EPS 1e-5f

#define MS512  ((size_t)M_PAD * 512)
#define MS2048 ((size_t)M_PAD * 2048)

typedef __attribute__((ext_vector_type(8))) short short8;   // bf16x8 frag (4 VGPR)
typedef __attribute__((ext_vector_type(4))) float f32x4;    // MFMA acc

__device__ __forceinline__ ushort f2bf(float f) {
    unsigned u = __float_as_uint(f);
    u += 0x7FFFu + ((u >> 16) & 1u);           // RNE
    return (ushort)(u >> 16);
}
__device__ __forceinline__ float bf2f(ushort h) {
    return __uint_as_float(((unsigned)h) << 16);
}
__device__ __forceinline__ int sel4(int4 v, int z) {
    return z == 0 ? v.x : z == 1 ? v.y : z == 2 ? v.z : v.w;
}

typedef __attribute__((address_space(3))) unsigned int lds_u32;
typedef __attribute__((address_space(1))) unsigned int glb_u32;
__device__ __forceinline__ void gl_lds16(const ushort* g, ushort* l) {
    __builtin_amdgcn_global_load_lds((glb_u32*)g, (lds_u32*)l, 16, 0, 0);
}

// ---------------- offsets ----------------
__global__ void k_offsets(const int* __restrict__ num_objs, int* __restrict__ offs) {
    if (threadIdx.x == 0) {
        int acc = 0;
        for (int b = 0; b < B_BATCH; ++b) { offs[b] = acc; acc += num_objs[b]; }
    }
}

// ---------------- f32 [M_REAL,512] -> bf16 [M_PAD,512], zero pad rows -------
__global__ __launch_bounds__(256)
void k_cvt_in(const float* __restrict__ src, ushort* __restrict__ dst) {
    int idx = blockIdx.x * 256 + threadIdx.x;   // one thread = 8 elems
    int row = idx >> 6;
    short8 o;
    if (row < M_REAL) {
        const float4* s = (const float4*)src + (size_t)idx * 2;
        float4 a = s[0], b = s[1];
        o[0] = (short)f2bf(a.x); o[1] = (short)f2bf(a.y);
        o[2] = (short)f2bf(a.z); o[3] = (short)f2bf(a.w);
        o[4] = (short)f2bf(b.x); o[5] = (short)f2bf(b.y);
        o[6] = (short)f2bf(b.z); o[7] = (short)f2bf(b.w);
    } else {
        o = (short8)0;
    }
    ((short8*)dst)[idx] = o;
}

// ---------------- bias concat: bqkv[e][1536] = cat(bq,bk,bv) -----------------
__global__ void k_cat_bias(const float* __restrict__ bq, const float* __restrict__ bk,
                           const float* __restrict__ bv, float* __restrict__ out) {
    int idx = blockIdx.x * 256 + threadIdx.x;
    if (idx >= 4 * 1536) return;
    int e = idx / 1536, c = idx - e * 1536;
    float v = (c < 512) ? bq[e * 512 + c] : (c < 1024) ? bk[e * 512 + c - 512]
                                                       : bv[e * 512 + c - 1024];
    out[idx] = v;
}

// ---------------- weight transpose+cvt: f32 [R,C] -> bf16 [C,R] --------------
__global__ __launch_bounds__(256)
void k_wt(const float* __restrict__ src, ushort* __restrict__ dst, int R, int C,
          size_t dstStride, size_t dstOff) {
    __shared__ float t[32][33];
    const float* s = src + (size_t)blockIdx.z * R * C;
    ushort* d = dst + (size_t)blockIdx.z * dstStride + dstOff;
    int tx = threadIdx.x & 31, ty = threadIdx.x >> 5;   // 32 x 8
    int r0 = blockIdx.y * 32, c0 = blockIdx.x * 32;
#pragma unroll
    for (int i = 0; i < 4; ++i)
        t[ty + i * 8][tx] = s[(size_t)(r0 + ty + i * 8) * C + c0 + tx];
    __syncthreads();
#pragma unroll
    for (int i = 0; i < 4; ++i)
        d[(size_t)(c0 + ty + i * 8) * R + r0 + tx] = f2bf(t[tx][ty + i * 8]);
}

// ---------------- bf16 MFMA GEMM: r9 K-loop + COALESCED LDS-bounce epilogue --
// K-loop: gl_lds dbuf + counted vmcnt(8) (verified r9). Epilogue: acc -> LDS
// f32 tile (aliases staging LDS, same 64KB) -> barrier -> row-major stores:
// thread t owns rows g*16+(t>>4), cols (t&15)*8 -> 16B/lane bf16, 32B/lane
// f32, contiguous across lanes (full 128B lines).
enum { EPI_BF16 = 0, EPI_BF16_RELU = 1, EPI_F32_RESF32 = 2, EPI_F32_RESBF16 = 3 };

template<int MODE>
__global__ __launch_bounds__(256)
void k_gemm16(const ushort* __restrict__ A, const ushort* __restrict__ A2, int bySplit,
              size_t zA, int lda,
              const ushort* __restrict__ Wb, size_t wSize, int4 widx, int K,
              const float* __restrict__ biasB, int biasStride,
              const void* __restrict__ resv, const void* __restrict__ resv2,
              int resSplit, size_t zRes,
              void* __restrict__ Cv, size_t zC, int ldc, int Mreal) {
    __shared__ __attribute__((aligned(16))) char smem[65536];
    ushort* AsBuf = (ushort*)smem;                 // [2][128*64] ushort (32KB)
    ushort* BsBuf = (ushort*)(smem + 32768);       // [2][128*64] ushort (32KB)
    float*  Cs    = (float*)smem;                  // [128][128] f32 (64KB, epilogue)
    const int tid = threadIdx.x;

    // ---- XCD-chunked remap: dispatch ordinal d -> contiguous work per XCD ----
    const int NX = gridDim.x, NY = gridDim.y;
    const int NB = NX * NY * (int)gridDim.z;
    int d = blockIdx.x + NX * (blockIdx.y + NY * blockIdx.z);
    int qq = NB >> 3, rr = NB & 7;
    int xcd = d & 7, idx = d >> 3;
    int work = (xcd < rr ? xcd * (qq + 1) : rr * (qq + 1) + (xcd - rr) * qq) + idx;
    const int z = work / (NX * NY);
    int rem = work - z * (NX * NY);
    const int panel = rem / NY;            // row-panel index (col-fastest within panel)
    const int colb = rem - panel * NY;
    const int row0 = panel * 128;
    const int col0 = colb * 128;

    const ushort* Ause = ((colb < bySplit) ? A : A2) + (size_t)z * zA;
    const ushort* Wt = Wb + (size_t)sel4(widx, z) * wSize;
    const float* bias = biasB + (size_t)sel4(widx, z) * biasStride;
    const int zi = (z < resSplit) ? z : z - resSplit;
    const float*  resF = (const float*)((z < resSplit) ? resv : resv2) + (size_t)zi * zRes;
    const ushort* resH = (const ushort*)((z < resSplit) ? resv : resv2) + (size_t)zi * zRes;
    ushort* C16 = (ushort*)Cv + (size_t)z * zC;
    float*  C32 = (float*)Cv + (size_t)z * zC;

    const int lane = tid & 63, wid = tid >> 6;
    const int wr = wid >> 1, wc = wid & 1;
    const int fr = lane & 15, fq = lane >> 4;

    int srow[4], scol[4], soff[4];
#pragma unroll
    for (int r = 0; r < 4; ++r) {
        int off = tid * 16 + r * 4096;
        int row = off >> 7;
        int cp  = (off >> 4) & 7;
        soff[r] = off;
        srow[r] = row;
        scol[r] = (cp ^ (row & 7)) * 8;
    }

    f32x4 acc[4][4];
#pragma unroll
    for (int m = 0; m < 4; ++m)
#pragma unroll
        for (int n = 0; n < 4; ++n) acc[m][n] = (f32x4){0.f, 0.f, 0.f, 0.f};

    const int nk = K >> 6;   // >= 8 for all our shapes

    auto stage = [&](int ktile, int bufi) {
        const int k0 = ktile << 6;
#pragma unroll
        for (int r = 0; r < 4; ++r)
            gl_lds16(Ause + (size_t)(row0 + srow[r]) * lda + k0 + scol[r],
                     (ushort*)((char*)(AsBuf + bufi * 8192) + soff[r]));
#pragma unroll
        for (int r = 0; r < 4; ++r)
            gl_lds16(Wt + (size_t)(col0 + srow[r]) * K + k0 + scol[r],
                     (ushort*)((char*)(BsBuf + bufi * 8192) + soff[r]));
    };

    // prologue: two tiles in flight (8 vmem instructions each)
    stage(0, 0);
    stage(1, 1);

    for (int kt = 0; kt < nk; ++kt) {
        const int cur = kt & 1;
        // wait until tile kt's 8 loads landed; tile kt+1's 8 stay in flight
        if (kt == nk - 1) asm volatile("s_waitcnt vmcnt(0)" ::: "memory");
        else              asm volatile("s_waitcnt vmcnt(8)" ::: "memory");
        __builtin_amdgcn_s_barrier();
        // ---- compute current tile ----
#pragma unroll
        for (int kk = 0; kk < 2; ++kk) {
            short8 av[4], bv[4];
#pragma unroll
            for (int m = 0; m < 4; ++m) {
                int row = wr * 64 + m * 16 + fr;
                int byte = row * 128 + (((kk * 4 + fq) ^ (row & 7)) << 4);
                av[m] = *(const short8*)((const char*)(AsBuf + cur * 8192) + byte);
            }
#pragma unroll
            for (int n = 0; n < 4; ++n) {
                int row = wc * 64 + n * 16 + fr;
                int byte = row * 128 + (((kk * 4 + fq) ^ (row & 7)) << 4);
                bv[n] = *(const short8*)((const char*)(BsBuf + cur * 8192) + byte);
            }
#pragma unroll
            for (int m = 0; m < 4; ++m)
#pragma unroll
                for (int n = 0; n < 4; ++n)
                    acc[m][n] = __builtin_amdgcn_mfma_f32_16x16x32_bf16(av[m], bv[n], acc[m][n], 0, 0, 0);
        }
        // write-after-read fence, then refill the buffer we just consumed
        if (kt + 2 < nk) {
            __builtin_amdgcn_s_barrier();
            stage(kt + 2, cur);
        }
    }

    // ---- epilogue: acc -> LDS f32 tile (aliases staging), then coalesced IO --
    __syncthreads();   // all waves done reading As/Bs before Cs overwrite
#pragma unroll
    for (int m = 0; m < 4; ++m)
#pragma unroll
        for (int n = 0; n < 4; ++n) {
            int r = wr * 64 + m * 16 + fq * 4;
            int c = wc * 64 + n * 16 + fr;
#pragma unroll
            for (int i = 0; i < 4; ++i)
                Cs[(r + i) * 128 + c] = acc[m][n][i];
        }
    __syncthreads();

    // store phase: thread t -> rows g*16 + (t>>4), cols (t&15)*8
    const int tr = tid >> 4, tc = tid & 15;
    float bias8[8];
#pragma unroll
    for (int j = 0; j < 8; ++j) bias8[j] = bias[col0 + tc * 8 + j];
#pragma unroll
    for (int g = 0; g < 8; ++g) {
        int r = g * 16 + tr;
        int gr = row0 + r;
        size_t obase = (size_t)gr * ldc + col0 + tc * 8;
        const float* crow = &Cs[r * 128 + tc * 8];
        float v[8];
        *(float4*)&v[0] = *(const float4*)&crow[0];
        *(float4*)&v[4] = *(const float4*)&crow[4];
#pragma unroll
        for (int j = 0; j < 8; ++j) v[j] += bias8[j];
        if (MODE == EPI_BF16 || MODE == EPI_BF16_RELU) {
            short8 o;
#pragma unroll
            for (int j = 0; j < 8; ++j) {
                float x = (MODE == EPI_BF16_RELU) ? fmaxf(v[j], 0.f) : v[j];
                o[j] = (short)f2bf(x);
            }
            *(short8*)&C16[obase] = o;
        } else if (MODE == EPI_F32_RESF32) {
            if (gr < Mreal) {
                float4 r0 = *(const float4*)&resF[obase];
                float4 r1 = *(const float4*)&resF[obase + 4];
                v[0] += r0.x; v[1] += r0.y; v[2] += r0.z; v[3] += r0.w;
                v[4] += r1.x; v[5] += r1.y; v[6] += r1.z; v[7] += r1.w;
            }
            *(float4*)&C32[obase] = *(float4*)&v[0];
            *(float4*)&C32[obase + 4] = *(float4*)&v[4];
        } else {
            short8 rh = *(const short8*)&resH[obase];
#pragma unroll
            for (int j = 0; j < 8; ++j) v[j] += bf2f((ushort)rh[j]);
            *(float4*)&C32[obase] = *(float4*)&v[0];
            *(float4*)&C32[obase + 4] = *(float4*)&v[4];
        }
    }
}

// ---------------- MFMA segment attention (verified) --------------------------
#define KS_STRIDE 72
#define VT_STRIDE 104
#define PL_STRIDE 104

__global__ __launch_bounds__(256)
void k_attn_mfma(const ushort* __restrict__ QKV, const int* __restrict__ offs,
                 const int* __restrict__ num_objs, ushort* __restrict__ CTX) {
    __shared__ __attribute__((aligned(16))) ushort Ks[96 * KS_STRIDE];
    __shared__ __attribute__((aligned(16))) ushort Vt[64 * VT_STRIDE];
    __shared__ __attribute__((aligned(16))) ushort Pl[64 * PL_STRIDE];
    const int b = blockIdx.x, h = blockIdx.y;
    const int L = num_objs[b], off = offs[b];
    const int tid = threadIdx.x;
    const int lane = tid & 63, wid = tid >> 6;
    const int fr = lane & 15, fq = lane >> 4;

#pragma unroll
    for (int pass = 0; pass < 3; ++pass) {
        int j = pass * 32 + (tid >> 3);
        int d0 = (tid & 7) * 8;
        short8 kv = (short8)0, vv = (short8)0;
        if (j < L) {
            size_t base = (size_t)(off + j) * 1536 + h * 64 + d0;
            kv = *(const short8*)(QKV + base + 512);
            vv = *(const short8*)(QKV + base + 1024);
        }
        *(short8*)&Ks[j * KS_STRIDE + d0] = kv;
#pragma unroll
        for (int e = 0; e < 8; ++e) Vt[(d0 + e) * VT_STRIDE + j] = (ushort)vv[e];
    }
    __syncthreads();

    const int nkb = (L + 15) >> 4;
    const int nkc = (nkb + 1) >> 1;

    for (int qb = wid; qb < 6; qb += 4) {
        if (qb >= nkb) continue;
        const int q0 = qb * 16;
        const int qrow = q0 + fr;
        const int qc = (qrow < L) ? qrow : (L - 1);
        const ushort* qbase = QKV + (size_t)(off + qc) * 1536 + h * 64 + fq * 8;
        short8 qf0 = *(const short8*)qbase;
        short8 qf1 = *(const short8*)(qbase + 32);

        f32x4 st[6];
#pragma unroll 6
        for (int kb = 0; kb < nkb; ++kb) {
            short8 a0 = *(const short8*)&Ks[(kb * 16 + fr) * KS_STRIDE + fq * 8];
            short8 a1 = *(const short8*)&Ks[(kb * 16 + fr) * KS_STRIDE + 32 + fq * 8];
            f32x4 acc = (f32x4){0.f, 0.f, 0.f, 0.f};
            acc = __builtin_amdgcn_mfma_f32_16x16x32_bf16(a0, qf0, acc, 0, 0, 0);
            acc = __builtin_amdgcn_mfma_f32_16x16x32_bf16(a1, qf1, acc, 0, 0, 0);
            st[kb] = acc;
        }

        float m = -1e30f;
#pragma unroll 6
        for (int kb = 0; kb < nkb; ++kb)
#pragma unroll
            for (int i = 0; i < 4; ++i) {
                int k = kb * 16 + fq * 4 + i;
                if (k < L) m = fmaxf(m, st[kb][i] * 0.125f);
            }
        m = fmaxf(m, __shfl_xor(m, 16));
        m = fmaxf(m, __shfl_xor(m, 32));
        float sum = 0.f;
        float pv[6][4];
#pragma unroll
        for (int kb = 0; kb < 6; ++kb)
#pragma unroll
            for (int i = 0; i < 4; ++i) {
                float p = 0.f;
                if (kb < nkb) {
                    int k = kb * 16 + fq * 4 + i;
                    if (k < L) p = __expf(st[kb][i] * 0.125f - m);
                }
                pv[kb][i] = p;
                sum += p;
            }
        sum += __shfl_xor(sum, 16);
        sum += __shfl_xor(sum, 32);
        float inv = 1.f / sum;

        ushort* prow = &Pl[(wid * 16 + fr) * PL_STRIDE];
#pragma unroll
        for (int kb = 0; kb < 6; ++kb) {
            unsigned lo = (unsigned)f2bf(pv[kb][0]) | ((unsigned)f2bf(pv[kb][1]) << 16);
            unsigned hi = (unsigned)f2bf(pv[kb][2]) | ((unsigned)f2bf(pv[kb][3]) << 16);
            *(unsigned*)&prow[kb * 16 + fq * 4]     = lo;
            *(unsigned*)&prow[kb * 16 + fq * 4 + 2] = hi;
        }

        f32x4 ct[4];
#pragma unroll
        for (int db = 0; db < 4; ++db) ct[db] = (f32x4){0.f, 0.f, 0.f, 0.f};
        const ushort* prd = &Pl[(wid * 16 + fr) * PL_STRIDE];
#pragma unroll 3
        for (int kc = 0; kc < nkc; ++kc) {
            short8 pf = *(const short8*)&prd[kc * 32 + fq * 8];
#pragma unroll
            for (int db = 0; db < 4; ++db) {
                short8 vf = *(const short8*)&Vt[(db * 16 + fr) * VT_STRIDE + kc * 32 + fq * 8];
                ct[db] = __builtin_amdgcn_mfma_f32_16x16x32_bf16(vf, pf, ct[db], 0, 0, 0);
            }
        }

        if (qrow < L) {
            ushort* crow = CTX + (size_t)(off + qrow) * 512 + h * 64;
#pragma unroll
            for (int db = 0; db < 4; ++db) {
                ushort4 o;
                o.x = f2bf(ct[db][0] * inv);
                o.y = f2bf(ct[db][1] * inv);
                o.z = f2bf(ct[db][2] * inv);
                o.w = f2bf(ct[db][3] * inv);
                *(ushort4*)&crow[db * 16 + fq * 4] = o;
            }
        }
    }
}

// ---------------- LayerNorm helpers (one wave per row) -----------------------
__device__ __forceinline__ void ln_row8(const float* __restrict__ X, const float* __restrict__ g,
                                        const float* __restrict__ be, int lane, float* o) {
    const float4* x4 = (const float4*)X;
    float4 v0 = x4[2 * lane], v1 = x4[2 * lane + 1];
    float s = v0.x + v0.y + v0.z + v0.w + v1.x + v1.y + v1.z + v1.w;
    for (int t = 32; t > 0; t >>= 1) s += __shfl_xor(s, t);
    float mean = s * (1.f / 512.f);
    float dd[8] = {v0.x - mean, v0.y - mean, v0.z - mean, v0.w - mean,
                   v1.x - mean, v1.y - mean, v1.z - mean, v1.w - mean};
    float vs = 0.f;
#pragma unroll
    for (int i = 0; i < 8; ++i) vs += dd[i] * dd[i];
    for (int t = 32; t > 0; t >>= 1) vs += __shfl_xor(vs, t);
    float rstd = rsqrtf(vs * (1.f / 512.f) + LN_EPS);
    const float4* g4 = (const float4*)g;
    const float4* b4 = (const float4*)be;
    float4 ga = g4[2 * lane], gb = g4[2 * lane + 1];
    float4 ba = b4[2 * lane], bb = b4[2 * lane + 1];
    o[0] = dd[0] * rstd * ga.x + ba.x;  o[1] = dd[1] * rstd * ga.y + ba.y;
    o[2] = dd[2] * rstd * ga.z + ba.z;  o[3] = dd[3] * rstd * ga.w + ba.w;
    o[4] = dd[4] * rstd * gb.x + bb.x;  o[5] = dd[5] * rstd * gb.y + bb.y;
    o[6] = dd[6] * rstd * gb.z + bb.z;  o[7] = dd[7] * rstd * gb.w + bb.w;
}

// LN1 batched over z encoders (z=blockIdx.y), bf16 out. 4 rows per block.
__global__ __launch_bounds__(256)
void k_ln1(const float* __restrict__ Xb, const float* __restrict__ gB,
           const float* __restrict__ beB, ushort* __restrict__ outB, int4 widx) {
    int e = blockIdx.y;
    int row = blockIdx.x * 4 + (threadIdx.x >> 6);
    int lane = threadIdx.x & 63;
    int pi = sel4(widx, e);
    float o[8];
    ln_row8(Xb + (size_t)e * MS512 + (size_t)row * 512, gB + pi * 512, beB + pi * 512, lane, o);
    short8 o8;
#pragma unroll
    for (int i = 0; i < 8; ++i) o8[i] = (short)f2bf(o[i]);
    ((short8*)(outB + (size_t)e * MS512 + (size_t)row * 512))[lane] = o8;
}

// LN2 + pair sum: dst = LN(Ob2[0]; pA) + LN(Ob2[1]; pB)
__global__ __launch_bounds__(256)
void k_ln2pair(const float* __restrict__ Ob2, const float* __restrict__ gB,
               const float* __restrict__ beB, float* __restrict__ dst,
               int pA, int pB) {
    int row = blockIdx.x * 4 + (threadIdx.x >> 6);
    int lane = threadIdx.x & 63;
    float oA[8], oB[8];
    ln_row8(Ob2 + (size_t)row * 512,         gB + pA * 512, beB + pA * 512, lane, oA);
    ln_row8(Ob2 + MS512 + (size_t)row * 512, gB + pB * 512, beB + pB * 512, lane, oB);
    if (row < M_REAL) {
        float* drow = dst + (size_t)row * 512;
        float4 s0, s1;
        s0.x = oA[0] + oB[0]; s0.y = oA[1] + oB[1]; s0.z = oA[2] + oB[2]; s0.w = oA[3] + oB[3];
        s1.x = oA[4] + oB[4]; s1.y = oA[5] + oB[5]; s1.z = oA[6] + oB[6]; s1.w = oA[7] + oB[7];
        ((float4*)drow)[2 * lane] = s0;
        ((float4*)drow)[2 * lane + 1] = s1;
    }
}

// ---------------- driver ------------------------------------------------------
extern "C" void kernel_launch(void* const* d_in, const int* in_sizes, int n_in,
                              void* d_out, int out_size, void* d_ws, size_t ws_size,
                              hipStream_t stream) {
    const float* vis = (const float*)d_in[0];
    const float* txt = (const float*)d_in[1];
    const float* Wq  = (const float*)d_in[2];
    const float* bq  = (const float*)d_in[3];
    const float* Wk  = (const float*)d_in[4];
    const float* bk  = (const float*)d_in[5];
    const float* Wv  = (const float*)d_in[6];
    const float* bv  = (const float*)d_in[7];
    const float* Wo  = (const float*)d_in[8];
    const float* bo  = (const float*)d_in[9];
    const float* g1  = (const float*)d_in[10];
    const float* be1 = (const float*)d_in[11];
    const float* W1  = (const float*)d_in[12];
    const float* b1  = (const float*)d_in[13];
    const float* W2  = (const float*)d_in[14];
    const float* b2  = (const float*)d_in[15];
    const float* g2  = (const float*)d_in[16];
    const float* be2 = (const float*)d_in[17];
    const int* num_objs = (const int*)d_in[18];

    // ---- workspace (aliased unions): 190.3 MB total ----
    char* p = (char*)d_ws;
    ushort* QKV16  = (ushort*)p;               // U1: [M_PAD][1536] bf16 (QKV phase)
    ushort* H16    = (ushort*)p;               // U1: [M_PAD][2048] bf16 (FFN phase)
    p += (size_t)M_PAD * 2048 * 2;
    ushort* CTX2   = (ushort*)p;               // U2: [2][M_PAD][512] bf16 (attn out)
    ushort* O116_2 = (ushort*)p;               // U2 alias: LN1 out (CTX dead after Wo)
    p += (size_t)2 * MS512 * 2;
    float*  Ob2    = (float*)p;                // U3: [2][M_PAD][512] f32
    p += (size_t)2 * MS512 * 4;
    ushort* vis16  = (ushort*)p;  p += MS512 * 2;
    ushort* txt16  = (ushort*)p;  p += MS512 * 2;
    ushort* wqkv16 = (ushort*)p;  p += (size_t)4 * 1536 * 512 * 2;
    ushort* wo16   = (ushort*)p;  p += (size_t)4 * 512 * 512 * 2;
    ushort* w116   = (ushort*)p;  p += (size_t)4 * 2048 * 512 * 2;
    ushort* w216   = (ushort*)p;  p += (size_t)4 * 512 * 2048 * 2;
    float*  bqkv   = (float*)p;   p += (size_t)4 * 1536 * 4;
    int*    offs   = (int*)p;     p += 1024;

    float* outv = (float*)d_out;
    float* outt = outv + (size_t)M_REAL * 512;

    k_offsets<<<1, 64, 0, stream>>>(num_objs, offs);
    k_cvt_in<<<3360, 256, 0, stream>>>(vis, vis16);
    k_cvt_in<<<3360, 256, 0, stream>>>(txt, txt16);
    k_cat_bias<<<24, 256, 0, stream>>>(bq, bk, bv, bqkv);
    // wqkv[e] = [1536][512]: rows 0-511 Wq^T, 512-1023 Wk^T, 1024-1535 Wv^T
    k_wt<<<dim3(16, 16, 4), 256, 0, stream>>>(Wq, wqkv16, 512, 512, (size_t)1536 * 512, 0);
    k_wt<<<dim3(16, 16, 4), 256, 0, stream>>>(Wk, wqkv16, 512, 512, (size_t)1536 * 512, (size_t)512 * 512);
    k_wt<<<dim3(16, 16, 4), 256, 0, stream>>>(Wv, wqkv16, 512, 512, (size_t)1536 * 512, (size_t)1024 * 512);
    k_wt<<<dim3(16, 16, 4), 256, 0, stream>>>(Wo, wo16, 512, 512, (size_t)512 * 512, 0);
    k_wt<<<dim3(64, 16, 4), 256, 0, stream>>>(W1, w116, 512, 2048, (size_t)2048 * 512, 0);
    k_wt<<<dim3(16, 64, 4), 256, 0, stream>>>(W2, w216, 2048, 512, (size_t)512 * 2048, 0);

    // e order: 0=tsa(txt,txt,p1) 1=tca(txt,vis,p3) 2=vsa(vis,vis,p0) 3=vca(vis,txt,p2)
    const int perm[4] = {1, 3, 0, 2};
    const ushort* qsrc[4]  = {txt16, txt16, vis16, vis16};
    const ushort* kvsrc[4] = {txt16, vis16, vis16, txt16};

    for (int pr = 0; pr < 2; ++pr) {
        // ---- QKV (fused N=1536) + attention, per encoder of the pair ----
        for (int z = 0; z < 2; ++z) {
            int e = 2 * pr + z;
            int4 wz = make_int4(perm[e], perm[e], perm[e], perm[e]);
            k_gemm16<EPI_BF16><<<dim3(105, 12, 1), 256, 0, stream>>>(
                qsrc[e], kvsrc[e], 4, 0, 512,
                wqkv16, (size_t)1536 * 512, wz, 512,
                bqkv, 1536,
                nullptr, nullptr, 8, 0,
                QKV16, 0, 1536, M_PAD);
            k_attn_mfma<<<dim3(B_BATCH, 8), 256, 0, stream>>>(
                QKV16, offs, num_objs, CTX2 + (size_t)z * MS512);
        }
        // ---- Wo (z=2): Ob2[z] = CTX2[z]@Wo + bo + q_in (f32) ----
        int4 wzp = make_int4(perm[2 * pr], perm[2 * pr + 1], 0, 0);
        const float* resq = pr ? vis : txt;
        k_gemm16<EPI_F32_RESF32><<<dim3(105, 4, 2), 256, 0, stream>>>(
            CTX2, CTX2, 99, MS512, 512,
            wo16, (size_t)512 * 512, wzp, 512,
            bo, 512,
            resq, resq, 2, 0,
            Ob2, MS512, 512, M_REAL);
        // ---- LN1 (z=2) -> bf16 (overwrites CTX alias) ----
        k_ln1<<<dim3(3360, 2), 256, 0, stream>>>(Ob2, g1, be1, O116_2, wzp);
        // ---- FFN per encoder (H16 single-buffer) ----
        for (int z = 0; z < 2; ++z) {
            int e = 2 * pr + z;
            int4 wz = make_int4(perm[e], perm[e], perm[e], perm[e]);
            k_gemm16<EPI_BF16_RELU><<<dim3(105, 16, 1), 256, 0, stream>>>(
                O116_2 + (size_t)z * MS512, O116_2, 99, 0, 512,
                w116, (size_t)2048 * 512, wz, 512,
                b1, 2048,
                nullptr, nullptr, 8, 0,
                H16, 0, 2048, M_PAD);
            k_gemm16<EPI_F32_RESBF16><<<dim3(105, 4, 1), 256, 0, stream>>>(
                H16, H16, 99, 0, 2048,
                w216, (size_t)512 * 2048, wz, 2048,
                b2, 512,
                O116_2 + (size_t)z * MS512, nullptr, 8, 0,
                Ob2 + (size_t)z * MS512, 0, 512, M_PAD);
        }
        // ---- LN2 + pair sum -> output ----
        k_ln2pair<<<3360, 256, 0, stream>>>(Ob2, g2, be2, pr ? outv : outt,
                                            pr ? 0 : 1, pr ? 2 : 3);
    }
}

// Round 14
// 675.576 us; speedup vs baseline: 1.2006x; 1.0826x over previous
//
#include <hip/hip_runtime.h>
#include <math.h>

#define M_REAL 13320
#define M_PAD  13440          // 105 * 128
#define B_BATCH 240
#define LN_EPS 1e-5f

#define MS512  ((size_t)M_PAD * 512)
#define MS1536 ((size_t)M_PAD * 1536)

typedef __attribute__((ext_vector_type(8))) short short8;   // bf16x8 frag (4 VGPR)
typedef __attribute__((ext_vector_type(4))) float f32x4;    // MFMA acc

__device__ __forceinline__ ushort f2bf(float f) {
    unsigned u = __float_as_uint(f);
    u += 0x7FFFu + ((u >> 16) & 1u);           // RNE
    return (ushort)(u >> 16);
}
__device__ __forceinline__ float bf2f(ushort h) {
    return __uint_as_float(((unsigned)h) << 16);
}
__device__ __forceinline__ int sel4(int4 v, int z) {
    return z == 0 ? v.x : z == 1 ? v.y : z == 2 ? v.z : v.w;
}

typedef __attribute__((address_space(3))) unsigned int lds_u32;
typedef __attribute__((address_space(1))) unsigned int glb_u32;
__device__ __forceinline__ void gl_lds16(const ushort* g, ushort* l) {
    __builtin_amdgcn_global_load_lds((glb_u32*)g, (lds_u32*)l, 16, 0, 0);
}

// ---------------- offsets ----------------
__global__ void k_offsets(const int* __restrict__ num_objs, int* __restrict__ offs) {
    if (threadIdx.x == 0) {
        int acc = 0;
        for (int b = 0; b < B_BATCH; ++b) { offs[b] = acc; acc += num_objs[b]; }
    }
}

// ---------------- f32 [M_REAL,512] -> bf16 [M_PAD,512], zero pad rows -------
__global__ __launch_bounds__(256)
void k_cvt_in(const float* __restrict__ src, ushort* __restrict__ dst) {
    int idx = blockIdx.x * 256 + threadIdx.x;   // one thread = 8 elems
    int row = idx >> 6;
    short8 o;
    if (row < M_REAL) {
        const float4* s = (const float4*)src + (size_t)idx * 2;
        float4 a = s[0], b = s[1];
        o[0] = (short)f2bf(a.x); o[1] = (short)f2bf(a.y);
        o[2] = (short)f2bf(a.z); o[3] = (short)f2bf(a.w);
        o[4] = (short)f2bf(b.x); o[5] = (short)f2bf(b.y);
        o[6] = (short)f2bf(b.z); o[7] = (short)f2bf(b.w);
    } else {
        o = (short8)0;
    }
    ((short8*)dst)[idx] = o;
}

// ---------------- bias concat: bqkv[e][1536] = cat(bq,bk,bv) -----------------
__global__ void k_cat_bias(const float* __restrict__ bq, const float* __restrict__ bk,
                           const float* __restrict__ bv, float* __restrict__ out) {
    int idx = blockIdx.x * 256 + threadIdx.x;
    if (idx >= 4 * 1536) return;
    int e = idx / 1536, c = idx - e * 1536;
    float v = (c < 512) ? bq[e * 512 + c] : (c < 1024) ? bk[e * 512 + c - 512]
                                                       : bv[e * 512 + c - 1024];
    out[idx] = v;
}

// ---------------- weight transpose+cvt: f32 [R,C] -> bf16 [C,R] --------------
__global__ __launch_bounds__(256)
void k_wt(const float* __restrict__ src, ushort* __restrict__ dst, int R, int C,
          size_t dstStride, size_t dstOff) {
    __shared__ float t[32][33];
    const float* s = src + (size_t)blockIdx.z * R * C;
    ushort* d = dst + (size_t)blockIdx.z * dstStride + dstOff;
    int tx = threadIdx.x & 31, ty = threadIdx.x >> 5;   // 32 x 8
    int r0 = blockIdx.y * 32, c0 = blockIdx.x * 32;
#pragma unroll
    for (int i = 0; i < 4; ++i)
        t[ty + i * 8][tx] = s[(size_t)(r0 + ty + i * 8) * C + c0 + tx];
    __syncthreads();
#pragma unroll
    for (int i = 0; i < 4; ++i)
        d[(size_t)(c0 + ty + i * 8) * R + r0 + tx] = f2bf(t[tx][ty + i * 8]);
}

// ---------------- bf16 MFMA GEMM: r13 verified core, all-bf16 epilogues ------
// K-loop: gl_lds dbuf + counted vmcnt(8). Epilogue: acc -> LDS f32 tile
// (aliases staging LDS) -> coalesced bf16 stores (16B/lane, full lines).
// qkvz=1 enables per-z A-selection for fused QKV pairs:
//   Ause = (colb < bySplit || z == 0) ? A : A2   (kv differs only at z=1).
enum { EPI_BF16 = 0, EPI_BF16_RELU = 1, EPI_BF16_RESBF16 = 2 };

template<int MODE>
__global__ __launch_bounds__(256)
void k_gemm16(const ushort* __restrict__ A, const ushort* __restrict__ A2, int bySplit,
              int qkvz, size_t zA, int lda,
              const ushort* __restrict__ Wb, size_t wSize, int4 widx, int K,
              const float* __restrict__ biasB, int biasStride,
              const ushort* __restrict__ resv, const ushort* __restrict__ resv2,
              int resSplit, size_t zRes,
              ushort* __restrict__ Cv, size_t zC, int ldc) {
    __shared__ __attribute__((aligned(16))) char smem[65536];
    ushort* AsBuf = (ushort*)smem;                 // [2][128*64] ushort (32KB)
    ushort* BsBuf = (ushort*)(smem + 32768);       // [2][128*64] ushort (32KB)
    float*  Cs    = (float*)smem;                  // [128][128] f32 (64KB, epilogue)
    const int tid = threadIdx.x;

    // ---- XCD-chunked remap: dispatch ordinal d -> contiguous work per XCD ----
    const int NX = gridDim.x, NY = gridDim.y;
    const int NB = NX * NY * (int)gridDim.z;
    int d = blockIdx.x + NX * (blockIdx.y + NY * blockIdx.z);
    int qq = NB >> 3, rr = NB & 7;
    int xcd = d & 7, idx = d >> 3;
    int work = (xcd < rr ? xcd * (qq + 1) : rr * (qq + 1) + (xcd - rr) * qq) + idx;
    const int z = work / (NX * NY);
    int rem = work - z * (NX * NY);
    const int panel = rem / NY;            // row-panel index (col-fastest within panel)
    const int colb = rem - panel * NY;
    const int row0 = panel * 128;
    const int col0 = colb * 128;

    const bool useA = (colb < bySplit) || (qkvz && z == 0);
    const ushort* Ause = (useA ? A : A2) + (size_t)z * zA;
    const ushort* Wt = Wb + (size_t)sel4(widx, z) * wSize;
    const float* bias = biasB + (size_t)sel4(widx, z) * biasStride;
    const int zi = (z < resSplit) ? z : z - resSplit;
    const ushort* resH = ((z < resSplit) ? resv : resv2) + (size_t)zi * zRes;
    ushort* C16 = Cv + (size_t)z * zC;

    const int lane = tid & 63, wid = tid >> 6;
    const int wr = wid >> 1, wc = wid & 1;
    const int fr = lane & 15, fq = lane >> 4;

    int srow[4], scol[4], soff[4];
#pragma unroll
    for (int r = 0; r < 4; ++r) {
        int off = tid * 16 + r * 4096;
        int row = off >> 7;
        int cp  = (off >> 4) & 7;
        soff[r] = off;
        srow[r] = row;
        scol[r] = (cp ^ (row & 7)) * 8;
    }

    f32x4 acc[4][4];
#pragma unroll
    for (int m = 0; m < 4; ++m)
#pragma unroll
        for (int n = 0; n < 4; ++n) acc[m][n] = (f32x4){0.f, 0.f, 0.f, 0.f};

    const int nk = K >> 6;   // >= 8 for all our shapes

    auto stage = [&](int ktile, int bufi) {
        const int k0 = ktile << 6;
#pragma unroll
        for (int r = 0; r < 4; ++r)
            gl_lds16(Ause + (size_t)(row0 + srow[r]) * lda + k0 + scol[r],
                     (ushort*)((char*)(AsBuf + bufi * 8192) + soff[r]));
#pragma unroll
        for (int r = 0; r < 4; ++r)
            gl_lds16(Wt + (size_t)(col0 + srow[r]) * K + k0 + scol[r],
                     (ushort*)((char*)(BsBuf + bufi * 8192) + soff[r]));
    };

    // prologue: two tiles in flight (8 vmem instructions each)
    stage(0, 0);
    stage(1, 1);

    for (int kt = 0; kt < nk; ++kt) {
        const int cur = kt & 1;
        // wait until tile kt's 8 loads landed; tile kt+1's 8 stay in flight
        if (kt == nk - 1) asm volatile("s_waitcnt vmcnt(0)" ::: "memory");
        else              asm volatile("s_waitcnt vmcnt(8)" ::: "memory");
        __builtin_amdgcn_s_barrier();
        // ---- compute current tile ----
#pragma unroll
        for (int kk = 0; kk < 2; ++kk) {
            short8 av[4], bv[4];
#pragma unroll
            for (int m = 0; m < 4; ++m) {
                int row = wr * 64 + m * 16 + fr;
                int byte = row * 128 + (((kk * 4 + fq) ^ (row & 7)) << 4);
                av[m] = *(const short8*)((const char*)(AsBuf + cur * 8192) + byte);
            }
#pragma unroll
            for (int n = 0; n < 4; ++n) {
                int row = wc * 64 + n * 16 + fr;
                int byte = row * 128 + (((kk * 4 + fq) ^ (row & 7)) << 4);
                bv[n] = *(const short8*)((const char*)(BsBuf + cur * 8192) + byte);
            }
#pragma unroll
            for (int m = 0; m < 4; ++m)
#pragma unroll
                for (int n = 0; n < 4; ++n)
                    acc[m][n] = __builtin_amdgcn_mfma_f32_16x16x32_bf16(av[m], bv[n], acc[m][n], 0, 0, 0);
        }
        // write-after-read fence, then refill the buffer we just consumed
        if (kt + 2 < nk) {
            __builtin_amdgcn_s_barrier();
            stage(kt + 2, cur);
        }
    }

    // ---- epilogue: acc -> LDS f32 tile (aliases staging), then coalesced IO --
    __syncthreads();   // all waves done reading As/Bs before Cs overwrite
#pragma unroll
    for (int m = 0; m < 4; ++m)
#pragma unroll
        for (int n = 0; n < 4; ++n) {
            int r = wr * 64 + m * 16 + fq * 4;
            int c = wc * 64 + n * 16 + fr;
#pragma unroll
            for (int i = 0; i < 4; ++i)
                Cs[(r + i) * 128 + c] = acc[m][n][i];
        }
    __syncthreads();

    // store phase: thread t -> rows g*16 + (t>>4), cols (t&15)*8
    const int tr = tid >> 4, tc = tid & 15;
    float bias8[8];
#pragma unroll
    for (int j = 0; j < 8; ++j) bias8[j] = bias[col0 + tc * 8 + j];
#pragma unroll
    for (int g = 0; g < 8; ++g) {
        int r = g * 16 + tr;
        int gr = row0 + r;
        size_t obase = (size_t)gr * ldc + col0 + tc * 8;
        const float* crow = &Cs[r * 128 + tc * 8];
        float v[8];
        *(float4*)&v[0] = *(const float4*)&crow[0];
        *(float4*)&v[4] = *(const float4*)&crow[4];
#pragma unroll
        for (int j = 0; j < 8; ++j) v[j] += bias8[j];
        if (MODE == EPI_BF16_RESBF16) {
            short8 rh = *(const short8*)&resH[obase];
#pragma unroll
            for (int j = 0; j < 8; ++j) v[j] += bf2f((ushort)rh[j]);
        }
        short8 o;
#pragma unroll
        for (int j = 0; j < 8; ++j) {
            float x = (MODE == EPI_BF16_RELU) ? fmaxf(v[j], 0.f) : v[j];
            o[j] = (short)f2bf(x);
        }
        *(short8*)&C16[obase] = o;
    }
}

// ---------------- MFMA segment attention (verified; z-batched) ---------------
#define KS_STRIDE 72
#define VT_STRIDE 104
#define PL_STRIDE 104

__global__ __launch_bounds__(256)
void k_attn_mfma(const ushort* __restrict__ QKVb, const int* __restrict__ offs,
                 const int* __restrict__ num_objs, ushort* __restrict__ CTXb) {
    __shared__ __attribute__((aligned(16))) ushort Ks[96 * KS_STRIDE];
    __shared__ __attribute__((aligned(16))) ushort Vt[64 * VT_STRIDE];
    __shared__ __attribute__((aligned(16))) ushort Pl[64 * PL_STRIDE];
    const int b = blockIdx.x, h = blockIdx.y;
    const ushort* QKV = QKVb + (size_t)blockIdx.z * MS1536;
    ushort* CTX = CTXb + (size_t)blockIdx.z * MS512;
    const int L = num_objs[b], off = offs[b];
    const int tid = threadIdx.x;
    const int lane = tid & 63, wid = tid >> 6;
    const int fr = lane & 15, fq = lane >> 4;

#pragma unroll
    for (int pass = 0; pass < 3; ++pass) {
        int j = pass * 32 + (tid >> 3);
        int d0 = (tid & 7) * 8;
        short8 kv = (short8)0, vv = (short8)0;
        if (j < L) {
            size_t base = (size_t)(off + j) * 1536 + h * 64 + d0;
            kv = *(const short8*)(QKV + base + 512);
            vv = *(const short8*)(QKV + base + 1024);
        }
        *(short8*)&Ks[j * KS_STRIDE + d0] = kv;
#pragma unroll
        for (int e = 0; e < 8; ++e) Vt[(d0 + e) * VT_STRIDE + j] = (ushort)vv[e];
    }
    __syncthreads();

    const int nkb = (L + 15) >> 4;
    const int nkc = (nkb + 1) >> 1;

    for (int qb = wid; qb < 6; qb += 4) {
        if (qb >= nkb) continue;
        const int q0 = qb * 16;
        const int qrow = q0 + fr;
        const int qc = (qrow < L) ? qrow : (L - 1);
        const ushort* qbase = QKV + (size_t)(off + qc) * 1536 + h * 64 + fq * 8;
        short8 qf0 = *(const short8*)qbase;
        short8 qf1 = *(const short8*)(qbase + 32);

        f32x4 st[6];
#pragma unroll 6
        for (int kb = 0; kb < nkb; ++kb) {
            short8 a0 = *(const short8*)&Ks[(kb * 16 + fr) * KS_STRIDE + fq * 8];
            short8 a1 = *(const short8*)&Ks[(kb * 16 + fr) * KS_STRIDE + 32 + fq * 8];
            f32x4 acc = (f32x4){0.f, 0.f, 0.f, 0.f};
            acc = __builtin_amdgcn_mfma_f32_16x16x32_bf16(a0, qf0, acc, 0, 0, 0);
            acc = __builtin_amdgcn_mfma_f32_16x16x32_bf16(a1, qf1, acc, 0, 0, 0);
            st[kb] = acc;
        }

        float m = -1e30f;
#pragma unroll 6
        for (int kb = 0; kb < nkb; ++kb)
#pragma unroll
            for (int i = 0; i < 4; ++i) {
                int k = kb * 16 + fq * 4 + i;
                if (k < L) m = fmaxf(m, st[kb][i] * 0.125f);
            }
        m = fmaxf(m, __shfl_xor(m, 16));
        m = fmaxf(m, __shfl_xor(m, 32));
        float sum = 0.f;
        float pv[6][4];
#pragma unroll
        for (int kb = 0; kb < 6; ++kb)
#pragma unroll
            for (int i = 0; i < 4; ++i) {
                float p = 0.f;
                if (kb < nkb) {
                    int k = kb * 16 + fq * 4 + i;
                    if (k < L) p = __expf(st[kb][i] * 0.125f - m);
                }
                pv[kb][i] = p;
                sum += p;
            }
        sum += __shfl_xor(sum, 16);
        sum += __shfl_xor(sum, 32);
        float inv = 1.f / sum;

        ushort* prow = &Pl[(wid * 16 + fr) * PL_STRIDE];
#pragma unroll
        for (int kb = 0; kb < 6; ++kb) {
            unsigned lo = (unsigned)f2bf(pv[kb][0]) | ((unsigned)f2bf(pv[kb][1]) << 16);
            unsigned hi = (unsigned)f2bf(pv[kb][2]) | ((unsigned)f2bf(pv[kb][3]) << 16);
            *(unsigned*)&prow[kb * 16 + fq * 4]     = lo;
            *(unsigned*)&prow[kb * 16 + fq * 4 + 2] = hi;
        }

        f32x4 ct[4];
#pragma unroll
        for (int db = 0; db < 4; ++db) ct[db] = (f32x4){0.f, 0.f, 0.f, 0.f};
        const ushort* prd = &Pl[(wid * 16 + fr) * PL_STRIDE];
#pragma unroll 3
        for (int kc = 0; kc < nkc; ++kc) {
            short8 pf = *(const short8*)&prd[kc * 32 + fq * 8];
#pragma unroll
            for (int db = 0; db < 4; ++db) {
                short8 vf = *(const short8*)&Vt[(db * 16 + fr) * VT_STRIDE + kc * 32 + fq * 8];
                ct[db] = __builtin_amdgcn_mfma_f32_16x16x32_bf16(vf, pf, ct[db], 0, 0, 0);
            }
        }

        if (qrow < L) {
            ushort* crow = CTX + (size_t)(off + qrow) * 512 + h * 64;
#pragma unroll
            for (int db = 0; db < 4; ++db) {
                ushort4 o;
                o.x = f2bf(ct[db][0] * inv);
                o.y = f2bf(ct[db][1] * inv);
                o.z = f2bf(ct[db][2] * inv);
                o.w = f2bf(ct[db][3] * inv);
                *(ushort4*)&crow[db * 16 + fq * 4] = o;
            }
        }
    }
}

// ---------------- LayerNorm helpers (one wave per row, bf16 input) -----------
__device__ __forceinline__ void ln_row8_bf16(const ushort* __restrict__ X,
                                             const float* __restrict__ g,
                                             const float* __restrict__ be,
                                             int lane, float* o) {
    short8 x = ((const short8*)X)[lane];
    float xv[8];
#pragma unroll
    for (int i = 0; i < 8; ++i) xv[i] = bf2f((ushort)x[i]);
    float s = 0.f;
#pragma unroll
    for (int i = 0; i < 8; ++i) s += xv[i];
    for (int t = 32; t > 0; t >>= 1) s += __shfl_xor(s, t);
    float mean = s * (1.f / 512.f);
    float vs = 0.f;
#pragma unroll
    for (int i = 0; i < 8; ++i) { xv[i] -= mean; vs += xv[i] * xv[i]; }
    for (int t = 32; t > 0; t >>= 1) vs += __shfl_xor(vs, t);
    float rstd = rsqrtf(vs * (1.f / 512.f) + LN_EPS);
    const float4* g4 = (const float4*)g;
    const float4* b4 = (const float4*)be;
    float4 ga = g4[2 * lane], gb = g4[2 * lane + 1];
    float4 ba = b4[2 * lane], bb = b4[2 * lane + 1];
    o[0] = xv[0] * rstd * ga.x + ba.x;  o[1] = xv[1] * rstd * ga.y + ba.y;
    o[2] = xv[2] * rstd * ga.z + ba.z;  o[3] = xv[3] * rstd * ga.w + ba.w;
    o[4] = xv[4] * rstd * gb.x + bb.x;  o[5] = xv[5] * rstd * gb.y + bb.y;
    o[6] = xv[6] * rstd * gb.z + bb.z;  o[7] = xv[7] * rstd * gb.w + bb.w;
}

// LN1 batched over z encoders (z=blockIdx.y), bf16 in/out. 4 rows per block.
__global__ __launch_bounds__(256)
void k_ln1(const ushort* __restrict__ Xb, const float* __restrict__ gB,
           const float* __restrict__ beB, ushort* __restrict__ outB, int4 widx) {
    int e = blockIdx.y;
    int row = blockIdx.x * 4 + (threadIdx.x >> 6);
    int lane = threadIdx.x & 63;
    int pi = sel4(widx, e);
    float o[8];
    ln_row8_bf16(Xb + (size_t)e * MS512 + (size_t)row * 512, gB + pi * 512, beB + pi * 512, lane, o);
    short8 o8;
#pragma unroll
    for (int i = 0; i < 8; ++i) o8[i] = (short)f2bf(o[i]);
    ((short8*)(outB + (size_t)e * MS512 + (size_t)row * 512))[lane] = o8;
}

// LN2 + pair sum: dst = LN(Ob2[0]; pA) + LN(Ob2[1]; pB)  (bf16 input)
__global__ __launch_bounds__(256)
void k_ln2pair(const ushort* __restrict__ Ob2, const float* __restrict__ gB,
               const float* __restrict__ beB, float* __restrict__ dst,
               int pA, int pB) {
    int row = blockIdx.x * 4 + (threadIdx.x >> 6);
    int lane = threadIdx.x & 63;
    float oA[8], oB[8];
    ln_row8_bf16(Ob2 + (size_t)row * 512,          gB + pA * 512, beB + pA * 512, lane, oA);
    ln_row8_bf16(Ob2 + MS512 + (size_t)row * 512,  gB + pB * 512, beB + pB * 512, lane, oB);
    if (row < M_REAL) {
        float* drow = dst + (size_t)row * 512;
        float4 s0, s1;
        s0.x = oA[0] + oB[0]; s0.y = oA[1] + oB[1]; s0.z = oA[2] + oB[2]; s0.w = oA[3] + oB[3];
        s1.x = oA[4] + oB[4]; s1.y = oA[5] + oB[5]; s1.z = oA[6] + oB[6]; s1.w = oA[7] + oB[7];
        ((float4*)drow)[2 * lane] = s0;
        ((float4*)drow)[2 * lane + 1] = s1;
    }
}

// ---------------- driver ------------------------------------------------------
extern "C" void kernel_launch(void* const* d_in, const int* in_sizes, int n_in,
                              void* d_out, int out_size, void* d_ws, size_t ws_size,
                              hipStream_t stream) {
    const float* vis = (const float*)d_in[0];
    const float* txt = (const float*)d_in[1];
    const float* Wq  = (const float*)d_in[2];
    const float* bq  = (const float*)d_in[3];
    const float* Wk  = (const float*)d_in[4];
    const float* bk  = (const float*)d_in[5];
    const float* Wv  = (const float*)d_in[6];
    const float* bv  = (const float*)d_in[7];
    const float* Wo  = (const float*)d_in[8];
    const float* bo  = (const float*)d_in[9];
    const float* g1  = (const float*)d_in[10];
    const float* be1 = (const float*)d_in[11];
    const float* W1  = (const float*)d_in[12];
    const float* b1  = (const float*)d_in[13];
    const float* W2  = (const float*)d_in[14];
    const float* b2  = (const float*)d_in[15];
    const float* g2  = (const float*)d_in[16];
    const float* be2 = (const float*)d_in[17];
    const int* num_objs = (const int*)d_in[18];

    // ---- workspace (aliased unions): ~216 MB total (proven-good <= 221 MB) --
    char* p = (char*)d_ws;
    ushort* QKV2   = (ushort*)p;               // U1: [2][M_PAD][1536] bf16 (QKV phase)
    ushort* H16    = (ushort*)p;               // U1 alias: [M_PAD][2048] bf16 (FFN phase)
    p += (size_t)2 * MS1536 * 2;               // 82.6 MB
    ushort* CTX2   = (ushort*)p;               // U2: [2][M_PAD][512] bf16 (attn out)
    ushort* O116_2 = (ushort*)p;               // U2 alias: LN1 out (CTX dead after Wo)
    p += (size_t)2 * MS512 * 2;                // 27.5 MB
    ushort* Ob2    = (ushort*)p;               // [2][M_PAD][512] bf16 (Wo out / FFN2 out)
    p += (size_t)2 * MS512 * 2;                // 27.5 MB
    ushort* vis16  = (ushort*)p;  p += MS512 * 2;
    ushort* txt16  = (ushort*)p;  p += MS512 * 2;
    ushort* wqkv16 = (ushort*)p;  p += (size_t)4 * 1536 * 512 * 2;
    ushort* wo16   = (ushort*)p;  p += (size_t)4 * 512 * 512 * 2;
    ushort* w116   = (ushort*)p;  p += (size_t)4 * 2048 * 512 * 2;
    ushort* w216   = (ushort*)p;  p += (size_t)4 * 512 * 2048 * 2;
    float*  bqkv   = (float*)p;   p += (size_t)4 * 1536 * 4;
    int*    offs   = (int*)p;     p += 1024;

    float* outv = (float*)d_out;
    float* outt = outv + (size_t)M_REAL * 512;

    k_offsets<<<1, 64, 0, stream>>>(num_objs, offs);
    k_cvt_in<<<3360, 256, 0, stream>>>(vis, vis16);
    k_cvt_in<<<3360, 256, 0, stream>>>(txt, txt16);
    k_cat_bias<<<24, 256, 0, stream>>>(bq, bk, bv, bqkv);
    // wqkv[e] = [1536][512]: rows 0-511 Wq^T, 512-1023 Wk^T, 1024-1535 Wv^T
    k_wt<<<dim3(16, 16, 4), 256, 0, stream>>>(Wq, wqkv16, 512, 512, (size_t)1536 * 512, 0);
    k_wt<<<dim3(16, 16, 4), 256, 0, stream>>>(Wk, wqkv16, 512, 512, (size_t)1536 * 512, (size_t)512 * 512);
    k_wt<<<dim3(16, 16, 4), 256, 0, stream>>>(Wv, wqkv16, 512, 512, (size_t)1536 * 512, (size_t)1024 * 512);
    k_wt<<<dim3(16, 16, 4), 256, 0, stream>>>(Wo, wo16, 512, 512, (size_t)512 * 512, 0);
    k_wt<<<dim3(64, 16, 4), 256, 0, stream>>>(W1, w116, 512, 2048, (size_t)2048 * 512, 0);
    k_wt<<<dim3(16, 64, 4), 256, 0, stream>>>(W2, w216, 2048, 512, (size_t)512 * 2048, 0);

    // e order: 0=tsa(txt,txt,p1) 1=tca(txt,vis,p3) 2=vsa(vis,vis,p0) 3=vca(vis,txt,p2)
    const int perm[4] = {1, 3, 0, 2};

    for (int pr = 0; pr < 2; ++pr) {
        const ushort* q16 = pr ? vis16 : txt16;    // q-src for both z of pair
        const ushort* o16 = pr ? txt16 : vis16;    // kv-src for z=1
        int4 wzp = make_int4(perm[2 * pr], perm[2 * pr + 1], 0, 0);

        // ---- QKV fused N=1536, z=2 batched (per-z A-selection via qkvz) ----
        k_gemm16<EPI_BF16><<<dim3(105, 12, 2), 256, 0, stream>>>(
            q16, o16, 4, 1, 0, 512,
            wqkv16, (size_t)1536 * 512, wzp, 512,
            bqkv, 1536,
            nullptr, nullptr, 8, 0,
            QKV2, MS1536, 1536);
        // ---- attention z=2 batched ----
        k_attn_mfma<<<dim3(B_BATCH, 8, 2), 256, 0, stream>>>(
            QKV2, offs, num_objs, CTX2);
        // ---- Wo (z=2): Ob2[z] = bf16(CTX2[z]@Wo + bo + q_in16)  ----
        k_gemm16<EPI_BF16_RESBF16><<<dim3(105, 4, 2), 256, 0, stream>>>(
            CTX2, CTX2, 99, 0, MS512, 512,
            wo16, (size_t)512 * 512, wzp, 512,
            bo, 512,
            q16, q16, 2, 0,
            Ob2, MS512, 512);
        // ---- LN1 (z=2) bf16 in/out (overwrites CTX alias) ----
        k_ln1<<<dim3(3360, 2), 256, 0, stream>>>(Ob2, g1, be1, O116_2, wzp);
        // ---- FFN per encoder (H16 single-buffer; aliases QKV2, now dead) ----
        for (int z = 0; z < 2; ++z) {
            int e = 2 * pr + z;
            int4 wz = make_int4(perm[e], perm[e], perm[e], perm[e]);
            k_gemm16<EPI_BF16_RELU><<<dim3(105, 16, 1), 256, 0, stream>>>(
                O116_2 + (size_t)z * MS512, O116_2, 99, 0, 0, 512,
                w116, (size_t)2048 * 512, wz, 512,
                b1, 2048,
                nullptr, nullptr, 8, 0,
                H16, 0, 2048);
            k_gemm16<EPI_BF16_RESBF16><<<dim3(105, 4, 1), 256, 0, stream>>>(
                H16, H16, 99, 0, 0, 2048,
                w216, (size_t)512 * 2048, wz, 2048,
                b2, 512,
                O116_2 + (size_t)z * MS512, nullptr, 8, 0,
                Ob2 + (size_t)z * MS512, 0, 512);
        }
        // ---- LN2 + pair sum -> output ----
        k_ln2pair<<<3360, 256, 0, stream>>>(Ob2, g2, be2, pr ? outv : outt,
                                            pr ? 0 : 1, pr ? 2 : 3);
    }
}

// Round 15
// 651.848 us; speedup vs baseline: 1.2443x; 1.0364x over previous
//
#include <hip/hip_runtime.h>
#include <math.h>

#define M_REAL 13320
#define M_PAD  13440          // 105 * 128
#define B_BATCH 240
#define LN_EPS 1e-5f

#define MS512  ((size_t)M_PAD * 512)
#define MS1536 ((size_t)M_PAD * 1536)
#define MS2048 ((size_t)M_PAD * 2048)

typedef __attribute__((ext_vector_type(8))) short short8;   // bf16x8 frag (4 VGPR)
typedef __attribute__((ext_vector_type(4))) float f32x4;    // MFMA acc

__device__ __forceinline__ ushort f2bf(float f) {
    unsigned u = __float_as_uint(f);
    u += 0x7FFFu + ((u >> 16) & 1u);           // RNE
    return (ushort)(u >> 16);
}
__device__ __forceinline__ float bf2f(ushort h) {
    return __uint_as_float(((unsigned)h) << 16);
}
__device__ __forceinline__ int sel4(int4 v, int z) {
    return z == 0 ? v.x : z == 1 ? v.y : z == 2 ? v.z : v.w;
}

typedef __attribute__((address_space(3))) unsigned int lds_u32;
typedef __attribute__((address_space(1))) unsigned int glb_u32;
__device__ __forceinline__ void gl_lds16(const ushort* g, ushort* l) {
    __builtin_amdgcn_global_load_lds((glb_u32*)g, (lds_u32*)l, 16, 0, 0);
}

// ---------------- offsets ----------------
__global__ void k_offsets(const int* __restrict__ num_objs, int* __restrict__ offs) {
    if (threadIdx.x == 0) {
        int acc = 0;
        for (int b = 0; b < B_BATCH; ++b) { offs[b] = acc; acc += num_objs[b]; }
    }
}

// ---------------- f32 [M_REAL,512] -> bf16 [M_PAD,512], zero pad rows -------
__global__ __launch_bounds__(256)
void k_cvt_in(const float* __restrict__ src, ushort* __restrict__ dst) {
    int idx = blockIdx.x * 256 + threadIdx.x;   // one thread = 8 elems
    int row = idx >> 6;
    short8 o;
    if (row < M_REAL) {
        const float4* s = (const float4*)src + (size_t)idx * 2;
        float4 a = s[0], b = s[1];
        o[0] = (short)f2bf(a.x); o[1] = (short)f2bf(a.y);
        o[2] = (short)f2bf(a.z); o[3] = (short)f2bf(a.w);
        o[4] = (short)f2bf(b.x); o[5] = (short)f2bf(b.y);
        o[6] = (short)f2bf(b.z); o[7] = (short)f2bf(b.w);
    } else {
        o = (short8)0;
    }
    ((short8*)dst)[idx] = o;
}

// ---------------- bias concat: bqkv[e][1536] = cat(bq,bk,bv) -----------------
__global__ void k_cat_bias(const float* __restrict__ bq, const float* __restrict__ bk,
                           const float* __restrict__ bv, float* __restrict__ out) {
    int idx = blockIdx.x * 256 + threadIdx.x;
    if (idx >= 4 * 1536) return;
    int e = idx / 1536, c = idx - e * 1536;
    float v = (c < 512) ? bq[e * 512 + c] : (c < 1024) ? bk[e * 512 + c - 512]
                                                       : bv[e * 512 + c - 1024];
    out[idx] = v;
}

// ---------------- weight transpose+cvt: f32 [R,C] -> bf16 [C,R] --------------
__global__ __launch_bounds__(256)
void k_wt(const float* __restrict__ src, ushort* __restrict__ dst, int R, int C,
          size_t dstStride, size_t dstOff) {
    __shared__ float t[32][33];
    const float* s = src + (size_t)blockIdx.z * R * C;
    ushort* d = dst + (size_t)blockIdx.z * dstStride + dstOff;
    int tx = threadIdx.x & 31, ty = threadIdx.x >> 5;   // 32 x 8
    int r0 = blockIdx.y * 32, c0 = blockIdx.x * 32;
#pragma unroll
    for (int i = 0; i < 4; ++i)
        t[ty + i * 8][tx] = s[(size_t)(r0 + ty + i * 8) * C + c0 + tx];
    __syncthreads();
#pragma unroll
    for (int i = 0; i < 4; ++i)
        d[(size_t)(c0 + ty + i * 8) * R + r0 + tx] = f2bf(t[tx][ty + i * 8]);
}

// ---------------- bf16 MFMA GEMM: r13 verified core, all-bf16 epilogues ------
// K-loop: gl_lds dbuf + counted vmcnt(8). Epilogue: acc -> LDS f32 tile
// (aliases staging LDS) -> coalesced bf16 stores (16B/lane, full lines).
// qkvz=1 enables per-z A-selection for fused QKV pairs:
//   Ause = (colb < bySplit || z == 0) ? A : A2   (kv differs only at z=1).
enum { EPI_BF16 = 0, EPI_BF16_RELU = 1, EPI_BF16_RESBF16 = 2 };

template<int MODE>
__global__ __launch_bounds__(256)
void k_gemm16(const ushort* __restrict__ A, const ushort* __restrict__ A2, int bySplit,
              int qkvz, size_t zA, int lda,
              const ushort* __restrict__ Wb, size_t wSize, int4 widx, int K,
              const float* __restrict__ biasB, int biasStride,
              const ushort* __restrict__ resv, const ushort* __restrict__ resv2,
              int resSplit, size_t zRes,
              ushort* __restrict__ Cv, size_t zC, int ldc) {
    __shared__ __attribute__((aligned(16))) char smem[65536];
    ushort* AsBuf = (ushort*)smem;                 // [2][128*64] ushort (32KB)
    ushort* BsBuf = (ushort*)(smem + 32768);       // [2][128*64] ushort (32KB)
    float*  Cs    = (float*)smem;                  // [128][128] f32 (64KB, epilogue)
    const int tid = threadIdx.x;

    // ---- XCD-chunked remap: dispatch ordinal d -> contiguous work per XCD ----
    const int NX = gridDim.x, NY = gridDim.y;
    const int NB = NX * NY * (int)gridDim.z;
    int d = blockIdx.x + NX * (blockIdx.y + NY * blockIdx.z);
    int qq = NB >> 3, rr = NB & 7;
    int xcd = d & 7, idx = d >> 3;
    int work = (xcd < rr ? xcd * (qq + 1) : rr * (qq + 1) + (xcd - rr) * qq) + idx;
    const int z = work / (NX * NY);
    int rem = work - z * (NX * NY);
    const int panel = rem / NY;            // row-panel index (col-fastest within panel)
    const int colb = rem - panel * NY;
    const int row0 = panel * 128;
    const int col0 = colb * 128;

    const bool useA = (colb < bySplit) || (qkvz && z == 0);
    const ushort* Ause = (useA ? A : A2) + (size_t)z * zA;
    const ushort* Wt = Wb + (size_t)sel4(widx, z) * wSize;
    const float* bias = biasB + (size_t)sel4(widx, z) * biasStride;
    const int zi = (z < resSplit) ? z : z - resSplit;
    const ushort* resH = ((z < resSplit) ? resv : resv2) + (size_t)zi * zRes;
    ushort* C16 = Cv + (size_t)z * zC;

    const int lane = tid & 63, wid = tid >> 6;
    const int wr = wid >> 1, wc = wid & 1;
    const int fr = lane & 15, fq = lane >> 4;

    int srow[4], scol[4], soff[4];
#pragma unroll
    for (int r = 0; r < 4; ++r) {
        int off = tid * 16 + r * 4096;
        int row = off >> 7;
        int cp  = (off >> 4) & 7;
        soff[r] = off;
        srow[r] = row;
        scol[r] = (cp ^ (row & 7)) * 8;
    }

    f32x4 acc[4][4];
#pragma unroll
    for (int m = 0; m < 4; ++m)
#pragma unroll
        for (int n = 0; n < 4; ++n) acc[m][n] = (f32x4){0.f, 0.f, 0.f, 0.f};

    const int nk = K >> 6;   // >= 8 for all our shapes

    auto stage = [&](int ktile, int bufi) {
        const int k0 = ktile << 6;
#pragma unroll
        for (int r = 0; r < 4; ++r)
            gl_lds16(Ause + (size_t)(row0 + srow[r]) * lda + k0 + scol[r],
                     (ushort*)((char*)(AsBuf + bufi * 8192) + soff[r]));
#pragma unroll
        for (int r = 0; r < 4; ++r)
            gl_lds16(Wt + (size_t)(col0 + srow[r]) * K + k0 + scol[r],
                     (ushort*)((char*)(BsBuf + bufi * 8192) + soff[r]));
    };

    // prologue: two tiles in flight (8 vmem instructions each)
    stage(0, 0);
    stage(1, 1);

    for (int kt = 0; kt < nk; ++kt) {
        const int cur = kt & 1;
        // wait until tile kt's 8 loads landed; tile kt+1's 8 stay in flight
        if (kt == nk - 1) asm volatile("s_waitcnt vmcnt(0)" ::: "memory");
        else              asm volatile("s_waitcnt vmcnt(8)" ::: "memory");
        __builtin_amdgcn_s_barrier();
        // ---- compute current tile ----
#pragma unroll
        for (int kk = 0; kk < 2; ++kk) {
            short8 av[4], bv[4];
#pragma unroll
            for (int m = 0; m < 4; ++m) {
                int row = wr * 64 + m * 16 + fr;
                int byte = row * 128 + (((kk * 4 + fq) ^ (row & 7)) << 4);
                av[m] = *(const short8*)((const char*)(AsBuf + cur * 8192) + byte);
            }
#pragma unroll
            for (int n = 0; n < 4; ++n) {
                int row = wc * 64 + n * 16 + fr;
                int byte = row * 128 + (((kk * 4 + fq) ^ (row & 7)) << 4);
                bv[n] = *(const short8*)((const char*)(BsBuf + cur * 8192) + byte);
            }
#pragma unroll
            for (int m = 0; m < 4; ++m)
#pragma unroll
                for (int n = 0; n < 4; ++n)
                    acc[m][n] = __builtin_amdgcn_mfma_f32_16x16x32_bf16(av[m], bv[n], acc[m][n], 0, 0, 0);
        }
        // write-after-read fence, then refill the buffer we just consumed
        if (kt + 2 < nk) {
            __builtin_amdgcn_s_barrier();
            stage(kt + 2, cur);
        }
    }

    // ---- epilogue: acc -> LDS f32 tile (aliases staging), then coalesced IO --
    __syncthreads();   // all waves done reading As/Bs before Cs overwrite
#pragma unroll
    for (int m = 0; m < 4; ++m)
#pragma unroll
        for (int n = 0; n < 4; ++n) {
            int r = wr * 64 + m * 16 + fq * 4;
            int c = wc * 64 + n * 16 + fr;
#pragma unroll
            for (int i = 0; i < 4; ++i)
                Cs[(r + i) * 128 + c] = acc[m][n][i];
        }
    __syncthreads();

    // store phase: thread t -> rows g*16 + (t>>4), cols (t&15)*8
    const int tr = tid >> 4, tc = tid & 15;
    float bias8[8];
#pragma unroll
    for (int j = 0; j < 8; ++j) bias8[j] = bias[col0 + tc * 8 + j];
#pragma unroll
    for (int g = 0; g < 8; ++g) {
        int r = g * 16 + tr;
        int gr = row0 + r;
        size_t obase = (size_t)gr * ldc + col0 + tc * 8;
        const float* crow = &Cs[r * 128 + tc * 8];
        float v[8];
        *(float4*)&v[0] = *(const float4*)&crow[0];
        *(float4*)&v[4] = *(const float4*)&crow[4];
#pragma unroll
        for (int j = 0; j < 8; ++j) v[j] += bias8[j];
        if (MODE == EPI_BF16_RESBF16) {
            short8 rh = *(const short8*)&resH[obase];
#pragma unroll
            for (int j = 0; j < 8; ++j) v[j] += bf2f((ushort)rh[j]);
        }
        short8 o;
#pragma unroll
        for (int j = 0; j < 8; ++j) {
            float x = (MODE == EPI_BF16_RELU) ? fmaxf(v[j], 0.f) : v[j];
            o[j] = (short)f2bf(x);
        }
        *(short8*)&C16[obase] = o;
    }
}

// ---------------- MFMA segment attention (verified; z-batched) ---------------
#define KS_STRIDE 72
#define VT_STRIDE 104
#define PL_STRIDE 104

__global__ __launch_bounds__(256)
void k_attn_mfma(const ushort* __restrict__ QKVb, const int* __restrict__ offs,
                 const int* __restrict__ num_objs, ushort* __restrict__ CTXb) {
    __shared__ __attribute__((aligned(16))) ushort Ks[96 * KS_STRIDE];
    __shared__ __attribute__((aligned(16))) ushort Vt[64 * VT_STRIDE];
    __shared__ __attribute__((aligned(16))) ushort Pl[64 * PL_STRIDE];
    const int b = blockIdx.x, h = blockIdx.y;
    const ushort* QKV = QKVb + (size_t)blockIdx.z * MS1536;
    ushort* CTX = CTXb + (size_t)blockIdx.z * MS512;
    const int L = num_objs[b], off = offs[b];
    const int tid = threadIdx.x;
    const int lane = tid & 63, wid = tid >> 6;
    const int fr = lane & 15, fq = lane >> 4;

#pragma unroll
    for (int pass = 0; pass < 3; ++pass) {
        int j = pass * 32 + (tid >> 3);
        int d0 = (tid & 7) * 8;
        short8 kv = (short8)0, vv = (short8)0;
        if (j < L) {
            size_t base = (size_t)(off + j) * 1536 + h * 64 + d0;
            kv = *(const short8*)(QKV + base + 512);
            vv = *(const short8*)(QKV + base + 1024);
        }
        *(short8*)&Ks[j * KS_STRIDE + d0] = kv;
#pragma unroll
        for (int e = 0; e < 8; ++e) Vt[(d0 + e) * VT_STRIDE + j] = (ushort)vv[e];
    }
    __syncthreads();

    const int nkb = (L + 15) >> 4;
    const int nkc = (nkb + 1) >> 1;

    for (int qb = wid; qb < 6; qb += 4) {
        if (qb >= nkb) continue;
        const int q0 = qb * 16;
        const int qrow = q0 + fr;
        const int qc = (qrow < L) ? qrow : (L - 1);
        const ushort* qbase = QKV + (size_t)(off + qc) * 1536 + h * 64 + fq * 8;
        short8 qf0 = *(const short8*)qbase;
        short8 qf1 = *(const short8*)(qbase + 32);

        f32x4 st[6];
#pragma unroll 6
        for (int kb = 0; kb < nkb; ++kb) {
            short8 a0 = *(const short8*)&Ks[(kb * 16 + fr) * KS_STRIDE + fq * 8];
            short8 a1 = *(const short8*)&Ks[(kb * 16 + fr) * KS_STRIDE + 32 + fq * 8];
            f32x4 acc = (f32x4){0.f, 0.f, 0.f, 0.f};
            acc = __builtin_amdgcn_mfma_f32_16x16x32_bf16(a0, qf0, acc, 0, 0, 0);
            acc = __builtin_amdgcn_mfma_f32_16x16x32_bf16(a1, qf1, acc, 0, 0, 0);
            st[kb] = acc;
        }

        float m = -1e30f;
#pragma unroll 6
        for (int kb = 0; kb < nkb; ++kb)
#pragma unroll
            for (int i = 0; i < 4; ++i) {
                int k = kb * 16 + fq * 4 + i;
                if (k < L) m = fmaxf(m, st[kb][i] * 0.125f);
            }
        m = fmaxf(m, __shfl_xor(m, 16));
        m = fmaxf(m, __shfl_xor(m, 32));
        float sum = 0.f;
        float pv[6][4];
#pragma unroll
        for (int kb = 0; kb < 6; ++kb)
#pragma unroll
            for (int i = 0; i < 4; ++i) {
                float p = 0.f;
                if (kb < nkb) {
                    int k = kb * 16 + fq * 4 + i;
                    if (k < L) p = __expf(st[kb][i] * 0.125f - m);
                }
                pv[kb][i] = p;
                sum += p;
            }
        sum += __shfl_xor(sum, 16);
        sum += __shfl_xor(sum, 32);
        float inv = 1.f / sum;

        ushort* prow = &Pl[(wid * 16 + fr) * PL_STRIDE];
#pragma unroll
        for (int kb = 0; kb < 6; ++kb) {
            unsigned lo = (unsigned)f2bf(pv[kb][0]) | ((unsigned)f2bf(pv[kb][1]) << 16);
            unsigned hi = (unsigned)f2bf(pv[kb][2]) | ((unsigned)f2bf(pv[kb][3]) << 16);
            *(unsigned*)&prow[kb * 16 + fq * 4]     = lo;
            *(unsigned*)&prow[kb * 16 + fq * 4 + 2] = hi;
        }

        f32x4 ct[4];
#pragma unroll
        for (int db = 0; db < 4; ++db) ct[db] = (f32x4){0.f, 0.f, 0.f, 0.f};
        const ushort* prd = &Pl[(wid * 16 + fr) * PL_STRIDE];
#pragma unroll 3
        for (int kc = 0; kc < nkc; ++kc) {
            short8 pf = *(const short8*)&prd[kc * 32 + fq * 8];
#pragma unroll
            for (int db = 0; db < 4; ++db) {
                short8 vf = *(const short8*)&Vt[(db * 16 + fr) * VT_STRIDE + kc * 32 + fq * 8];
                ct[db] = __builtin_amdgcn_mfma_f32_16x16x32_bf16(vf, pf, ct[db], 0, 0, 0);
            }
        }

        if (qrow < L) {
            ushort* crow = CTX + (size_t)(off + qrow) * 512 + h * 64;
#pragma unroll
            for (int db = 0; db < 4; ++db) {
                ushort4 o;
                o.x = f2bf(ct[db][0] * inv);
                o.y = f2bf(ct[db][1] * inv);
                o.z = f2bf(ct[db][2] * inv);
                o.w = f2bf(ct[db][3] * inv);
                *(ushort4*)&crow[db * 16 + fq * 4] = o;
            }
        }
    }
}

// ---------------- LayerNorm helpers (one wave per row, bf16 input) -----------
__device__ __forceinline__ void ln_row8_bf16(const ushort* __restrict__ X,
                                             const float* __restrict__ g,
                                             const float* __restrict__ be,
                                             int lane, float* o) {
    short8 x = ((const short8*)X)[lane];
    float xv[8];
#pragma unroll
    for (int i = 0; i < 8; ++i) xv[i] = bf2f((ushort)x[i]);
    float s = 0.f;
#pragma unroll
    for (int i = 0; i < 8; ++i) s += xv[i];
    for (int t = 32; t > 0; t >>= 1) s += __shfl_xor(s, t);
    float mean = s * (1.f / 512.f);
    float vs = 0.f;
#pragma unroll
    for (int i = 0; i < 8; ++i) { xv[i] -= mean; vs += xv[i] * xv[i]; }
    for (int t = 32; t > 0; t >>= 1) vs += __shfl_xor(vs, t);
    float rstd = rsqrtf(vs * (1.f / 512.f) + LN_EPS);
    const float4* g4 = (const float4*)g;
    const float4* b4 = (const float4*)be;
    float4 ga = g4[2 * lane], gb = g4[2 * lane + 1];
    float4 ba = b4[2 * lane], bb = b4[2 * lane + 1];
    o[0] = xv[0] * rstd * ga.x + ba.x;  o[1] = xv[1] * rstd * ga.y + ba.y;
    o[2] = xv[2] * rstd * ga.z + ba.z;  o[3] = xv[3] * rstd * ga.w + ba.w;
    o[4] = xv[4] * rstd * gb.x + bb.x;  o[5] = xv[5] * rstd * gb.y + bb.y;
    o[6] = xv[6] * rstd * gb.z + bb.z;  o[7] = xv[7] * rstd * gb.w + bb.w;
}

// LN1 batched over z encoders (z=blockIdx.y), bf16 in/out. 4 rows per block.
__global__ __launch_bounds__(256)
void k_ln1(const ushort* __restrict__ Xb, const float* __restrict__ gB,
           const float* __restrict__ beB, ushort* __restrict__ outB, int4 widx) {
    int e = blockIdx.y;
    int row = blockIdx.x * 4 + (threadIdx.x >> 6);
    int lane = threadIdx.x & 63;
    int pi = sel4(widx, e);
    float o[8];
    ln_row8_bf16(Xb + (size_t)e * MS512 + (size_t)row * 512, gB + pi * 512, beB + pi * 512, lane, o);
    short8 o8;
#pragma unroll
    for (int i = 0; i < 8; ++i) o8[i] = (short)f2bf(o[i]);
    ((short8*)(outB + (size_t)e * MS512 + (size_t)row * 512))[lane] = o8;
}

// LN2 + pair sum: dst = LN(Ob2[0]; pA) + LN(Ob2[1]; pB)  (bf16 input)
__global__ __launch_bounds__(256)
void k_ln2pair(const ushort* __restrict__ Ob2, const float* __restrict__ gB,
               const float* __restrict__ beB, float* __restrict__ dst,
               int pA, int pB) {
    int row = blockIdx.x * 4 + (threadIdx.x >> 6);
    int lane = threadIdx.x & 63;
    float oA[8], oB[8];
    ln_row8_bf16(Ob2 + (size_t)row * 512,          gB + pA * 512, beB + pA * 512, lane, oA);
    ln_row8_bf16(Ob2 + MS512 + (size_t)row * 512,  gB + pB * 512, beB + pB * 512, lane, oB);
    if (row < M_REAL) {
        float* drow = dst + (size_t)row * 512;
        float4 s0, s1;
        s0.x = oA[0] + oB[0]; s0.y = oA[1] + oB[1]; s0.z = oA[2] + oB[2]; s0.w = oA[3] + oB[3];
        s1.x = oA[4] + oB[4]; s1.y = oA[5] + oB[5]; s1.z = oA[6] + oB[6]; s1.w = oA[7] + oB[7];
        ((float4*)drow)[2 * lane] = s0;
        ((float4*)drow)[2 * lane + 1] = s1;
    }
}

// ---------------- driver ------------------------------------------------------
extern "C" void kernel_launch(void* const* d_in, const int* in_sizes, int n_in,
                              void* d_out, int out_size, void* d_ws, size_t ws_size,
                              hipStream_t stream) {
    const float* vis = (const float*)d_in[0];
    const float* txt = (const float*)d_in[1];
    const float* Wq  = (const float*)d_in[2];
    const float* bq  = (const float*)d_in[3];
    const float* Wk  = (const float*)d_in[4];
    const float* bk  = (const float*)d_in[5];
    const float* Wv  = (const float*)d_in[6];
    const float* bv  = (const float*)d_in[7];
    const float* Wo  = (const float*)d_in[8];
    const float* bo  = (const float*)d_in[9];
    const float* g1  = (const float*)d_in[10];
    const float* be1 = (const float*)d_in[11];
    const float* W1  = (const float*)d_in[12];
    const float* b1  = (const float*)d_in[13];
    const float* W2  = (const float*)d_in[14];
    const float* b2  = (const float*)d_in[15];
    const float* g2  = (const float*)d_in[16];
    const float* be2 = (const float*)d_in[17];
    const int* num_objs = (const int*)d_in[18];

    // ---- workspace (aliased unions): ~218 MB total (proven-good <= 220 MB) --
    char* p = (char*)d_ws;
    ushort* QKV2   = (ushort*)p;               // U1: [2][M_PAD][1536] bf16 (QKV phase)
    ushort* H2     = (ushort*)p;               // U1 alias: [2][M_PAD][2048] bf16 (FFN)
    p += (size_t)2 * MS2048 * 2;               // 110.1 MB
    ushort* CTX2   = (ushort*)p;               // U2: [2][M_PAD][512] bf16 (attn out)
    ushort* O116_2 = (ushort*)p;               // U2 alias: LN1 out (CTX dead after Wo)
    p += (size_t)2 * MS512 * 2;                // 27.5 MB
    ushort* Ob2    = (ushort*)p;               // [2][M_PAD][512] bf16 (Wo out / FFN2 out)
    p += (size_t)2 * MS512 * 2;                // 27.5 MB
    ushort* vis16  = (ushort*)p;  p += MS512 * 2;
    ushort* txt16  = (ushort*)p;  p += MS512 * 2;
    ushort* wqkv16 = (ushort*)p;  p += (size_t)4 * 1536 * 512 * 2;
    ushort* wo16   = (ushort*)p;  p += (size_t)4 * 512 * 512 * 2;
    ushort* w116   = (ushort*)p;  p += (size_t)4 * 2048 * 512 * 2;
    ushort* w216   = (ushort*)p;  p += (size_t)4 * 512 * 2048 * 2;
    float*  bqkv   = (float*)p;   p += (size_t)4 * 1536 * 4;
    int*    offs   = (int*)p;     p += 1024;

    float* outv = (float*)d_out;
    float* outt = outv + (size_t)M_REAL * 512;

    k_offsets<<<1, 64, 0, stream>>>(num_objs, offs);
    k_cvt_in<<<3360, 256, 0, stream>>>(vis, vis16);
    k_cvt_in<<<3360, 256, 0, stream>>>(txt, txt16);
    k_cat_bias<<<24, 256, 0, stream>>>(bq, bk, bv, bqkv);
    // wqkv[e] = [1536][512]: rows 0-511 Wq^T, 512-1023 Wk^T, 1024-1535 Wv^T
    k_wt<<<dim3(16, 16, 4), 256, 0, stream>>>(Wq, wqkv16, 512, 512, (size_t)1536 * 512, 0);
    k_wt<<<dim3(16, 16, 4), 256, 0, stream>>>(Wk, wqkv16, 512, 512, (size_t)1536 * 512, (size_t)512 * 512);
    k_wt<<<dim3(16, 16, 4), 256, 0, stream>>>(Wv, wqkv16, 512, 512, (size_t)1536 * 512, (size_t)1024 * 512);
    k_wt<<<dim3(16, 16, 4), 256, 0, stream>>>(Wo, wo16, 512, 512, (size_t)512 * 512, 0);
    k_wt<<<dim3(64, 16, 4), 256, 0, stream>>>(W1, w116, 512, 2048, (size_t)2048 * 512, 0);
    k_wt<<<dim3(16, 64, 4), 256, 0, stream>>>(W2, w216, 2048, 512, (size_t)512 * 2048, 0);

    // e order: 0=tsa(txt,txt,p1) 1=tca(txt,vis,p3) 2=vsa(vis,vis,p0) 3=vca(vis,txt,p2)
    const int perm[4] = {1, 3, 0, 2};

    for (int pr = 0; pr < 2; ++pr) {
        const ushort* q16 = pr ? vis16 : txt16;    // q-src for both z of pair
        const ushort* o16 = pr ? txt16 : vis16;    // kv-src for z=1
        int4 wzp = make_int4(perm[2 * pr], perm[2 * pr + 1], 0, 0);

        // ---- QKV fused N=1536, z=2 batched (per-z A-selection via qkvz) ----
        k_gemm16<EPI_BF16><<<dim3(105, 12, 2), 256, 0, stream>>>(
            q16, o16, 4, 1, 0, 512,
            wqkv16, (size_t)1536 * 512, wzp, 512,
            bqkv, 1536,
            nullptr, nullptr, 8, 0,
            QKV2, MS1536, 1536);
        // ---- attention z=2 batched ----
        k_attn_mfma<<<dim3(B_BATCH, 8, 2), 256, 0, stream>>>(
            QKV2, offs, num_objs, CTX2);
        // ---- Wo (z=2): Ob2[z] = bf16(CTX2[z]@Wo + bo + q_in16)  ----
        k_gemm16<EPI_BF16_RESBF16><<<dim3(105, 4, 2), 256, 0, stream>>>(
            CTX2, CTX2, 99, 0, MS512, 512,
            wo16, (size_t)512 * 512, wzp, 512,
            bo, 512,
            q16, q16, 2, 0,
            Ob2, MS512, 512);
        // ---- LN1 (z=2) bf16 in/out (overwrites CTX alias) ----
        k_ln1<<<dim3(3360, 2), 256, 0, stream>>>(Ob2, g1, be1, O116_2, wzp);
        // ---- FFN z=2 batched (H2 aliases QKV2, dead after Wo) ----
        k_gemm16<EPI_BF16_RELU><<<dim3(105, 16, 2), 256, 0, stream>>>(
            O116_2, O116_2, 99, 0, MS512, 512,
            w116, (size_t)2048 * 512, wzp, 512,
            b1, 2048,
            nullptr, nullptr, 8, 0,
            H2, MS2048, 2048);
        k_gemm16<EPI_BF16_RESBF16><<<dim3(105, 4, 2), 256, 0, stream>>>(
            H2, H2, 99, 0, MS2048, 2048,
            w216, (size_t)512 * 2048, wzp, 2048,
            b2, 512,
            O116_2, nullptr, 8, MS512,
            Ob2, MS512, 512);
        // ---- LN2 + pair sum -> output ----
        k_ln2pair<<<3360, 256, 0, stream>>>(Ob2, g2, be2, pr ? outv : outt,
                                            pr ? 0 : 1, pr ? 2 : 3);
    }
}

// Round 16
// 644.240 us; speedup vs baseline: 1.2590x; 1.0118x over previous
//
#include <hip/hip_runtime.h>
#include <math.h>

#define M_REAL 13320
#define M_PAD  13440          // 105 * 128
#define B_BATCH 240
#define LN_EPS 1e-5f

#define MS512  ((size_t)M_PAD * 512)
#define MS1536 ((size_t)M_PAD * 1536)
#define MS2048 ((size_t)M_PAD * 2048)

typedef __attribute__((ext_vector_type(8))) short short8;   // bf16x8 frag (4 VGPR)
typedef __attribute__((ext_vector_type(4))) float f32x4;    // MFMA acc

__device__ __forceinline__ ushort f2bf(float f) {
    unsigned u = __float_as_uint(f);
    u += 0x7FFFu + ((u >> 16) & 1u);           // RNE
    return (ushort)(u >> 16);
}
__device__ __forceinline__ float bf2f(ushort h) {
    return __uint_as_float(((unsigned)h) << 16);
}
__device__ __forceinline__ int sel4(int4 v, int z) {
    return z == 0 ? v.x : z == 1 ? v.y : z == 2 ? v.z : v.w;
}

typedef __attribute__((address_space(3))) unsigned int lds_u32;
typedef __attribute__((address_space(1))) unsigned int glb_u32;
__device__ __forceinline__ void gl_lds16(const ushort* g, ushort* l) {
    __builtin_amdgcn_global_load_lds((glb_u32*)g, (lds_u32*)l, 16, 0, 0);
}

// ---------------- f32 [M_REAL,512] -> bf16 [M_PAD,512], zero pad; z=2 -------
__global__ __launch_bounds__(256)
void k_cvt_in(const float* __restrict__ srcA, const float* __restrict__ srcB,
              ushort* __restrict__ dstA, ushort* __restrict__ dstB) {
    const float* src = blockIdx.y ? srcB : srcA;
    ushort* dst = blockIdx.y ? dstB : dstA;
    int idx = blockIdx.x * 256 + threadIdx.x;   // one thread = 8 elems
    int row = idx >> 6;
    short8 o;
    if (row < M_REAL) {
        const float4* s = (const float4*)src + (size_t)idx * 2;
        float4 a = s[0], b = s[1];
        o[0] = (short)f2bf(a.x); o[1] = (short)f2bf(a.y);
        o[2] = (short)f2bf(a.z); o[3] = (short)f2bf(a.w);
        o[4] = (short)f2bf(b.x); o[5] = (short)f2bf(b.y);
        o[6] = (short)f2bf(b.z); o[7] = (short)f2bf(b.w);
    } else {
        o = (short8)0;
    }
    ((short8*)dst)[idx] = o;
}

// ---------------- bias concat + offsets (fused) ------------------------------
__global__ void k_cat_bias(const float* __restrict__ bq, const float* __restrict__ bk,
                           const float* __restrict__ bv, float* __restrict__ out,
                           const int* __restrict__ num_objs, int* __restrict__ offs) {
    int idx = blockIdx.x * 256 + threadIdx.x;
    if (idx == 0) {
        int acc = 0;
        for (int b = 0; b < B_BATCH; ++b) { offs[b] = acc; acc += num_objs[b]; }
    }
    if (idx >= 4 * 1536) return;
    int e = idx / 1536, c = idx - e * 1536;
    float v = (c < 512) ? bq[e * 512 + c] : (c < 1024) ? bk[e * 512 + c - 512]
                                                       : bv[e * 512 + c - 1024];
    out[idx] = v;
}

// ---------------- 512x512 weight transpose+cvt, ALL FOUR in one (z=16) ------
// z = 4*group + e; group 0..2 -> wqkv16[e] rows group*512..; group 3 -> wo16[e]
__global__ __launch_bounds__(256)
void k_wt512(const float* __restrict__ Wq, const float* __restrict__ Wk,
             const float* __restrict__ Wv, const float* __restrict__ Wo,
             ushort* __restrict__ wqkv16, ushort* __restrict__ wo16) {
    __shared__ float t[32][33];
    int grp = blockIdx.z >> 2, e = blockIdx.z & 3;
    const float* s = (grp == 0 ? Wq : grp == 1 ? Wk : grp == 2 ? Wv : Wo)
                     + (size_t)e * 512 * 512;
    ushort* d = (grp < 3) ? (wqkv16 + (size_t)e * 1536 * 512 + (size_t)grp * 512 * 512)
                          : (wo16 + (size_t)e * 512 * 512);
    int tx = threadIdx.x & 31, ty = threadIdx.x >> 5;   // 32 x 8
    int r0 = blockIdx.y * 32, c0 = blockIdx.x * 32;
#pragma unroll
    for (int i = 0; i < 4; ++i)
        t[ty + i * 8][tx] = s[(size_t)(r0 + ty + i * 8) * 512 + c0 + tx];
    __syncthreads();
#pragma unroll
    for (int i = 0; i < 4; ++i)
        d[(size_t)(c0 + ty + i * 8) * 512 + r0 + tx] = f2bf(t[tx][ty + i * 8]);
}

// ---------------- generic weight transpose+cvt (W1, W2) ----------------------
__global__ __launch_bounds__(256)
void k_wt(const float* __restrict__ src, ushort* __restrict__ dst, int R, int C,
          size_t dstStride, size_t dstOff) {
    __shared__ float t[32][33];
    const float* s = src + (size_t)blockIdx.z * R * C;
    ushort* d = dst + (size_t)blockIdx.z * dstStride + dstOff;
    int tx = threadIdx.x & 31, ty = threadIdx.x >> 5;   // 32 x 8
    int r0 = blockIdx.y * 32, c0 = blockIdx.x * 32;
#pragma unroll
    for (int i = 0; i < 4; ++i)
        t[ty + i * 8][tx] = s[(size_t)(r0 + ty + i * 8) * C + c0 + tx];
    __syncthreads();
#pragma unroll
    for (int i = 0; i < 4; ++i)
        d[(size_t)(c0 + ty + i * 8) * R + r0 + tx] = f2bf(t[tx][ty + i * 8]);
}

// ---------------- bf16 MFMA GEMM: verified core, all-bf16 epilogues ----------
// K-loop: gl_lds dbuf + counted vmcnt(8). Epilogue: acc -> LDS f32 tile
// (aliases staging LDS) -> coalesced bf16 stores (16B/lane, full lines).
// qkvz=1 enables per-z A-selection for fused QKV pairs.
enum { EPI_BF16 = 0, EPI_BF16_RELU = 1, EPI_BF16_RESBF16 = 2 };

template<int MODE>
__global__ __launch_bounds__(256)
void k_gemm16(const ushort* __restrict__ A, const ushort* __restrict__ A2, int bySplit,
              int qkvz, size_t zA, int lda,
              const ushort* __restrict__ Wb, size_t wSize, int4 widx, int K,
              const float* __restrict__ biasB, int biasStride,
              const ushort* __restrict__ resv, const ushort* __restrict__ resv2,
              int resSplit, size_t zRes,
              ushort* __restrict__ Cv, size_t zC, int ldc) {
    __shared__ __attribute__((aligned(16))) char smem[65536];
    ushort* AsBuf = (ushort*)smem;                 // [2][128*64] ushort (32KB)
    ushort* BsBuf = (ushort*)(smem + 32768);       // [2][128*64] ushort (32KB)
    float*  Cs    = (float*)smem;                  // [128][128] f32 (64KB, epilogue)
    const int tid = threadIdx.x;

    // ---- XCD-chunked remap: dispatch ordinal d -> contiguous work per XCD ----
    const int NX = gridDim.x, NY = gridDim.y;
    const int NB = NX * NY * (int)gridDim.z;
    int d = blockIdx.x + NX * (blockIdx.y + NY * blockIdx.z);
    int qq = NB >> 3, rr = NB & 7;
    int xcd = d & 7, idx = d >> 3;
    int work = (xcd < rr ? xcd * (qq + 1) : rr * (qq + 1) + (xcd - rr) * qq) + idx;
    const int z = work / (NX * NY);
    int rem = work - z * (NX * NY);
    const int panel = rem / NY;            // row-panel index (col-fastest within panel)
    const int colb = rem - panel * NY;
    const int row0 = panel * 128;
    const int col0 = colb * 128;

    const bool useA = (colb < bySplit) || (qkvz && z == 0);
    const ushort* Ause = (useA ? A : A2) + (size_t)z * zA;
    const ushort* Wt = Wb + (size_t)sel4(widx, z) * wSize;
    const float* bias = biasB + (size_t)sel4(widx, z) * biasStride;
    const int zi = (z < resSplit) ? z : z - resSplit;
    const ushort* resH = ((z < resSplit) ? resv : resv2) + (size_t)zi * zRes;
    ushort* C16 = Cv + (size_t)z * zC;

    const int lane = tid & 63, wid = tid >> 6;
    const int wr = wid >> 1, wc = wid & 1;
    const int fr = lane & 15, fq = lane >> 4;

    int srow[4], scol[4], soff[4];
#pragma unroll
    for (int r = 0; r < 4; ++r) {
        int off = tid * 16 + r * 4096;
        int row = off >> 7;
        int cp  = (off >> 4) & 7;
        soff[r] = off;
        srow[r] = row;
        scol[r] = (cp ^ (row & 7)) * 8;
    }

    f32x4 acc[4][4];
#pragma unroll
    for (int m = 0; m < 4; ++m)
#pragma unroll
        for (int n = 0; n < 4; ++n) acc[m][n] = (f32x4){0.f, 0.f, 0.f, 0.f};

    const int nk = K >> 6;   // >= 8 for all our shapes

    auto stage = [&](int ktile, int bufi) {
        const int k0 = ktile << 6;
#pragma unroll
        for (int r = 0; r < 4; ++r)
            gl_lds16(Ause + (size_t)(row0 + srow[r]) * lda + k0 + scol[r],
                     (ushort*)((char*)(AsBuf + bufi * 8192) + soff[r]));
#pragma unroll
        for (int r = 0; r < 4; ++r)
            gl_lds16(Wt + (size_t)(col0 + srow[r]) * K + k0 + scol[r],
                     (ushort*)((char*)(BsBuf + bufi * 8192) + soff[r]));
    };

    // prologue: two tiles in flight (8 vmem instructions each)
    stage(0, 0);
    stage(1, 1);

    for (int kt = 0; kt < nk; ++kt) {
        const int cur = kt & 1;
        // wait until tile kt's 8 loads landed; tile kt+1's 8 stay in flight
        if (kt == nk - 1) asm volatile("s_waitcnt vmcnt(0)" ::: "memory");
        else              asm volatile("s_waitcnt vmcnt(8)" ::: "memory");
        __builtin_amdgcn_s_barrier();
        // ---- compute current tile ----
#pragma unroll
        for (int kk = 0; kk < 2; ++kk) {
            short8 av[4], bv[4];
#pragma unroll
            for (int m = 0; m < 4; ++m) {
                int row = wr * 64 + m * 16 + fr;
                int byte = row * 128 + (((kk * 4 + fq) ^ (row & 7)) << 4);
                av[m] = *(const short8*)((const char*)(AsBuf + cur * 8192) + byte);
            }
#pragma unroll
            for (int n = 0; n < 4; ++n) {
                int row = wc * 64 + n * 16 + fr;
                int byte = row * 128 + (((kk * 4 + fq) ^ (row & 7)) << 4);
                bv[n] = *(const short8*)((const char*)(BsBuf + cur * 8192) + byte);
            }
#pragma unroll
            for (int m = 0; m < 4; ++m)
#pragma unroll
                for (int n = 0; n < 4; ++n)
                    acc[m][n] = __builtin_amdgcn_mfma_f32_16x16x32_bf16(av[m], bv[n], acc[m][n], 0, 0, 0);
        }
        // write-after-read fence, then refill the buffer we just consumed
        if (kt + 2 < nk) {
            __builtin_amdgcn_s_barrier();
            stage(kt + 2, cur);
        }
    }

    // ---- epilogue: acc -> LDS f32 tile (aliases staging), then coalesced IO --
    __syncthreads();   // all waves done reading As/Bs before Cs overwrite
#pragma unroll
    for (int m = 0; m < 4; ++m)
#pragma unroll
        for (int n = 0; n < 4; ++n) {
            int r = wr * 64 + m * 16 + fq * 4;
            int c = wc * 64 + n * 16 + fr;
#pragma unroll
            for (int i = 0; i < 4; ++i)
                Cs[(r + i) * 128 + c] = acc[m][n][i];
        }
    __syncthreads();

    // store phase: thread t -> rows g*16 + (t>>4), cols (t&15)*8
    const int tr = tid >> 4, tc = tid & 15;
    float bias8[8];
#pragma unroll
    for (int j = 0; j < 8; ++j) bias8[j] = bias[col0 + tc * 8 + j];
#pragma unroll
    for (int g = 0; g < 8; ++g) {
        int r = g * 16 + tr;
        int gr = row0 + r;
        size_t obase = (size_t)gr * ldc + col0 + tc * 8;
        const float* crow = &Cs[r * 128 + tc * 8];
        float v[8];
        *(float4*)&v[0] = *(const float4*)&crow[0];
        *(float4*)&v[4] = *(const float4*)&crow[4];
#pragma unroll
        for (int j = 0; j < 8; ++j) v[j] += bias8[j];
        if (MODE == EPI_BF16_RESBF16) {
            short8 rh = *(const short8*)&resH[obase];
#pragma unroll
            for (int j = 0; j < 8; ++j) v[j] += bf2f((ushort)rh[j]);
        }
        short8 o;
#pragma unroll
        for (int j = 0; j < 8; ++j) {
            float x = (MODE == EPI_BF16_RELU) ? fmaxf(v[j], 0.f) : v[j];
            o[j] = (short)f2bf(x);
        }
        *(short8*)&C16[obase] = o;
    }
}

// ---------------- MFMA segment attention (verified; z-batched) ---------------
#define KS_STRIDE 72
#define VT_STRIDE 104
#define PL_STRIDE 104

__global__ __launch_bounds__(256)
void k_attn_mfma(const ushort* __restrict__ QKVb, const int* __restrict__ offs,
                 const int* __restrict__ num_objs, ushort* __restrict__ CTXb) {
    __shared__ __attribute__((aligned(16))) ushort Ks[96 * KS_STRIDE];
    __shared__ __attribute__((aligned(16))) ushort Vt[64 * VT_STRIDE];
    __shared__ __attribute__((aligned(16))) ushort Pl[64 * PL_STRIDE];
    const int b = blockIdx.x, h = blockIdx.y;
    const ushort* QKV = QKVb + (size_t)blockIdx.z * MS1536;
    ushort* CTX = CTXb + (size_t)blockIdx.z * MS512;
    const int L = num_objs[b], off = offs[b];
    const int tid = threadIdx.x;
    const int lane = tid & 63, wid = tid >> 6;
    const int fr = lane & 15, fq = lane >> 4;

#pragma unroll
    for (int pass = 0; pass < 3; ++pass) {
        int j = pass * 32 + (tid >> 3);
        int d0 = (tid & 7) * 8;
        short8 kv = (short8)0, vv = (short8)0;
        if (j < L) {
            size_t base = (size_t)(off + j) * 1536 + h * 64 + d0;
            kv = *(const short8*)(QKV + base + 512);
            vv = *(const short8*)(QKV + base + 1024);
        }
        *(short8*)&Ks[j * KS_STRIDE + d0] = kv;
#pragma unroll
        for (int e = 0; e < 8; ++e) Vt[(d0 + e) * VT_STRIDE + j] = (ushort)vv[e];
    }
    __syncthreads();

    const int nkb = (L + 15) >> 4;
    const int nkc = (nkb + 1) >> 1;

    for (int qb = wid; qb < 6; qb += 4) {
        if (qb >= nkb) continue;
        const int q0 = qb * 16;
        const int qrow = q0 + fr;
        const int qc = (qrow < L) ? qrow : (L - 1);
        const ushort* qbase = QKV + (size_t)(off + qc) * 1536 + h * 64 + fq * 8;
        short8 qf0 = *(const short8*)qbase;
        short8 qf1 = *(const short8*)(qbase + 32);

        f32x4 st[6];
#pragma unroll 6
        for (int kb = 0; kb < nkb; ++kb) {
            short8 a0 = *(const short8*)&Ks[(kb * 16 + fr) * KS_STRIDE + fq * 8];
            short8 a1 = *(const short8*)&Ks[(kb * 16 + fr) * KS_STRIDE + 32 + fq * 8];
            f32x4 acc = (f32x4){0.f, 0.f, 0.f, 0.f};
            acc = __builtin_amdgcn_mfma_f32_16x16x32_bf16(a0, qf0, acc, 0, 0, 0);
            acc = __builtin_amdgcn_mfma_f32_16x16x32_bf16(a1, qf1, acc, 0, 0, 0);
            st[kb] = acc;
        }

        float m = -1e30f;
#pragma unroll 6
        for (int kb = 0; kb < nkb; ++kb)
#pragma unroll
            for (int i = 0; i < 4; ++i) {
                int k = kb * 16 + fq * 4 + i;
                if (k < L) m = fmaxf(m, st[kb][i] * 0.125f);
            }
        m = fmaxf(m, __shfl_xor(m, 16));
        m = fmaxf(m, __shfl_xor(m, 32));
        float sum = 0.f;
        float pv[6][4];
#pragma unroll
        for (int kb = 0; kb < 6; ++kb)
#pragma unroll
            for (int i = 0; i < 4; ++i) {
                float p = 0.f;
                if (kb < nkb) {
                    int k = kb * 16 + fq * 4 + i;
                    if (k < L) p = __expf(st[kb][i] * 0.125f - m);
                }
                pv[kb][i] = p;
                sum += p;
            }
        sum += __shfl_xor(sum, 16);
        sum += __shfl_xor(sum, 32);
        float inv = 1.f / sum;

        ushort* prow = &Pl[(wid * 16 + fr) * PL_STRIDE];
#pragma unroll
        for (int kb = 0; kb < 6; ++kb) {
            unsigned lo = (unsigned)f2bf(pv[kb][0]) | ((unsigned)f2bf(pv[kb][1]) << 16);
            unsigned hi = (unsigned)f2bf(pv[kb][2]) | ((unsigned)f2bf(pv[kb][3]) << 16);
            *(unsigned*)&prow[kb * 16 + fq * 4]     = lo;
            *(unsigned*)&prow[kb * 16 + fq * 4 + 2] = hi;
        }

        f32x4 ct[4];
#pragma unroll
        for (int db = 0; db < 4; ++db) ct[db] = (f32x4){0.f, 0.f, 0.f, 0.f};
        const ushort* prd = &Pl[(wid * 16 + fr) * PL_STRIDE];
#pragma unroll 3
        for (int kc = 0; kc < nkc; ++kc) {
            short8 pf = *(const short8*)&prd[kc * 32 + fq * 8];
#pragma unroll
            for (int db = 0; db < 4; ++db) {
                short8 vf = *(const short8*)&Vt[(db * 16 + fr) * VT_STRIDE + kc * 32 + fq * 8];
                ct[db] = __builtin_amdgcn_mfma_f32_16x16x32_bf16(vf, pf, ct[db], 0, 0, 0);
            }
        }

        if (qrow < L) {
            ushort* crow = CTX + (size_t)(off + qrow) * 512 + h * 64;
#pragma unroll
            for (int db = 0; db < 4; ++db) {
                ushort4 o;
                o.x = f2bf(ct[db][0] * inv);
                o.y = f2bf(ct[db][1] * inv);
                o.z = f2bf(ct[db][2] * inv);
                o.w = f2bf(ct[db][3] * inv);
                *(ushort4*)&crow[db * 16 + fq * 4] = o;
            }
        }
    }
}

// ---------------- LayerNorm helpers (one wave per row, bf16 input) -----------
__device__ __forceinline__ void ln_row8_bf16(const ushort* __restrict__ X,
                                             const float* __restrict__ g,
                                             const float* __restrict__ be,
                                             int lane, float* o) {
    short8 x = ((const short8*)X)[lane];
    float xv[8];
#pragma unroll
    for (int i = 0; i < 8; ++i) xv[i] = bf2f((ushort)x[i]);
    float s = 0.f;
#pragma unroll
    for (int i = 0; i < 8; ++i) s += xv[i];
    for (int t = 32; t > 0; t >>= 1) s += __shfl_xor(s, t);
    float mean = s * (1.f / 512.f);
    float vs = 0.f;
#pragma unroll
    for (int i = 0; i < 8; ++i) { xv[i] -= mean; vs += xv[i] * xv[i]; }
    for (int t = 32; t > 0; t >>= 1) vs += __shfl_xor(vs, t);
    float rstd = rsqrtf(vs * (1.f / 512.f) + LN_EPS);
    const float4* g4 = (const float4*)g;
    const float4* b4 = (const float4*)be;
    float4 ga = g4[2 * lane], gb = g4[2 * lane + 1];
    float4 ba = b4[2 * lane], bb = b4[2 * lane + 1];
    o[0] = xv[0] * rstd * ga.x + ba.x;  o[1] = xv[1] * rstd * ga.y + ba.y;
    o[2] = xv[2] * rstd * ga.z + ba.z;  o[3] = xv[3] * rstd * ga.w + ba.w;
    o[4] = xv[4] * rstd * gb.x + bb.x;  o[5] = xv[5] * rstd * gb.y + bb.y;
    o[6] = xv[6] * rstd * gb.z + bb.z;  o[7] = xv[7] * rstd * gb.w + bb.w;
}

// LN1 batched over z encoders (z=blockIdx.y), bf16 in/out. 4 rows per block.
__global__ __launch_bounds__(256)
void k_ln1(const ushort* __restrict__ Xb, const float* __restrict__ gB,
           const float* __restrict__ beB, ushort* __restrict__ outB, int4 widx) {
    int e = blockIdx.y;
    int row = blockIdx.x * 4 + (threadIdx.x >> 6);
    int lane = threadIdx.x & 63;
    int pi = sel4(widx, e);
    float o[8];
    ln_row8_bf16(Xb + (size_t)e * MS512 + (size_t)row * 512, gB + pi * 512, beB + pi * 512, lane, o);
    short8 o8;
#pragma unroll
    for (int i = 0; i < 8; ++i) o8[i] = (short)f2bf(o[i]);
    ((short8*)(outB + (size_t)e * MS512 + (size_t)row * 512))[lane] = o8;
}

// LN2 + pair sum: dst = LN(Ob2[0]; pA) + LN(Ob2[1]; pB)  (bf16 input)
__global__ __launch_bounds__(256)
void k_ln2pair(const ushort* __restrict__ Ob2, const float* __restrict__ gB,
               const float* __restrict__ beB, float* __restrict__ dst,
               int pA, int pB) {
    int row = blockIdx.x * 4 + (threadIdx.x >> 6);
    int lane = threadIdx.x & 63;
    float oA[8], oB[8];
    ln_row8_bf16(Ob2 + (size_t)row * 512,          gB + pA * 512, beB + pA * 512, lane, oA);
    ln_row8_bf16(Ob2 + MS512 + (size_t)row * 512,  gB + pB * 512, beB + pB * 512, lane, oB);
    if (row < M_REAL) {
        float* drow = dst + (size_t)row * 512;
        float4 s0, s1;
        s0.x = oA[0] + oB[0]; s0.y = oA[1] + oB[1]; s0.z = oA[2] + oB[2]; s0.w = oA[3] + oB[3];
        s1.x = oA[4] + oB[4]; s1.y = oA[5] + oB[5]; s1.z = oA[6] + oB[6]; s1.w = oA[7] + oB[7];
        ((float4*)drow)[2 * lane] = s0;
        ((float4*)drow)[2 * lane + 1] = s1;
    }
}

// ---------------- driver ------------------------------------------------------
extern "C" void kernel_launch(void* const* d_in, const int* in_sizes, int n_in,
                              void* d_out, int out_size, void* d_ws, size_t ws_size,
                              hipStream_t stream) {
    const float* vis = (const float*)d_in[0];
    const float* txt = (const float*)d_in[1];
    const float* Wq  = (const float*)d_in[2];
    const float* bq  = (const float*)d_in[3];
    const float* Wk  = (const float*)d_in[4];
    const float* bk  = (const float*)d_in[5];
    const float* Wv  = (const float*)d_in[6];
    const float* bv  = (const float*)d_in[7];
    const float* Wo  = (const float*)d_in[8];
    const float* bo  = (const float*)d_in[9];
    const float* g1  = (const float*)d_in[10];
    const float* be1 = (const float*)d_in[11];
    const float* W1  = (const float*)d_in[12];
    const float* b1  = (const float*)d_in[13];
    const float* W2  = (const float*)d_in[14];
    const float* b2  = (const float*)d_in[15];
    const float* g2  = (const float*)d_in[16];
    const float* be2 = (const float*)d_in[17];
    const int* num_objs = (const int*)d_in[18];

    // ---- workspace (aliased unions): ~218 MB total (proven-good <= 220 MB) --
    char* p = (char*)d_ws;
    ushort* QKV2   = (ushort*)p;               // U1: [2][M_PAD][1536] bf16 (QKV phase)
    ushort* H2     = (ushort*)p;               // U1 alias: [2][M_PAD][2048] bf16 (FFN)
    p += (size_t)2 * MS2048 * 2;               // 110.1 MB
    ushort* CTX2   = (ushort*)p;               // U2: [2][M_PAD][512] bf16 (attn out)
    ushort* O116_2 = (ushort*)p;               // U2 alias: LN1 out (CTX dead after Wo)
    p += (size_t)2 * MS512 * 2;                // 27.5 MB
    ushort* Ob2    = (ushort*)p;               // [2][M_PAD][512] bf16 (Wo out / FFN2 out)
    p += (size_t)2 * MS512 * 2;                // 27.5 MB
    ushort* vis16  = (ushort*)p;  p += MS512 * 2;
    ushort* txt16  = (ushort*)p;  p += MS512 * 2;
    ushort* wqkv16 = (ushort*)p;  p += (size_t)4 * 1536 * 512 * 2;
    ushort* wo16   = (ushort*)p;  p += (size_t)4 * 512 * 512 * 2;
    ushort* w116   = (ushort*)p;  p += (size_t)4 * 2048 * 512 * 2;
    ushort* w216   = (ushort*)p;  p += (size_t)4 * 512 * 2048 * 2;
    float*  bqkv   = (float*)p;   p += (size_t)4 * 1536 * 4;
    int*    offs   = (int*)p;     p += 1024;

    float* outv = (float*)d_out;
    float* outt = outv + (size_t)M_REAL * 512;

    // ---- preamble: 5 dispatches (was 10) ----
    k_cvt_in<<<dim3(3360, 2), 256, 0, stream>>>(vis, txt, vis16, txt16);
    k_cat_bias<<<24, 256, 0, stream>>>(bq, bk, bv, bqkv, num_objs, offs);
    k_wt512<<<dim3(16, 16, 16), 256, 0, stream>>>(Wq, Wk, Wv, Wo, wqkv16, wo16);
    k_wt<<<dim3(64, 16, 4), 256, 0, stream>>>(W1, w116, 512, 2048, (size_t)2048 * 512, 0);
    k_wt<<<dim3(16, 64, 4), 256, 0, stream>>>(W2, w216, 2048, 512, (size_t)512 * 2048, 0);

    // e order: 0=tsa(txt,txt,p1) 1=tca(txt,vis,p3) 2=vsa(vis,vis,p0) 3=vca(vis,txt,p2)
    const int perm[4] = {1, 3, 0, 2};

    for (int pr = 0; pr < 2; ++pr) {
        const ushort* q16 = pr ? vis16 : txt16;    // q-src for both z of pair
        const ushort* o16 = pr ? txt16 : vis16;    // kv-src for z=1
        int4 wzp = make_int4(perm[2 * pr], perm[2 * pr + 1], 0, 0);

        // ---- QKV fused N=1536, z=2 batched (per-z A-selection via qkvz) ----
        k_gemm16<EPI_BF16><<<dim3(105, 12, 2), 256, 0, stream>>>(
            q16, o16, 4, 1, 0, 512,
            wqkv16, (size_t)1536 * 512, wzp, 512,
            bqkv, 1536,
            nullptr, nullptr, 8, 0,
            QKV2, MS1536, 1536);
        // ---- attention z=2 batched ----
        k_attn_mfma<<<dim3(B_BATCH, 8, 2), 256, 0, stream>>>(
            QKV2, offs, num_objs, CTX2);
        // ---- Wo (z=2): Ob2[z] = bf16(CTX2[z]@Wo + bo + q_in16)  ----
        k_gemm16<EPI_BF16_RESBF16><<<dim3(105, 4, 2), 256, 0, stream>>>(
            CTX2, CTX2, 99, 0, MS512, 512,
            wo16, (size_t)512 * 512, wzp, 512,
            bo, 512,
            q16, q16, 2, 0,
            Ob2, MS512, 512);
        // ---- LN1 (z=2) bf16 in/out (overwrites CTX alias) ----
        k_ln1<<<dim3(3360, 2), 256, 0, stream>>>(Ob2, g1, be1, O116_2, wzp);
        // ---- FFN z=2 batched (H2 aliases QKV2, dead after Wo) ----
        k_gemm16<EPI_BF16_RELU><<<dim3(105, 16, 2), 256, 0, stream>>>(
            O116_2, O116_2, 99, 0, MS512, 512,
            w116, (size_t)2048 * 512, wzp, 512,
            b1, 2048,
            nullptr, nullptr, 8, 0,
            H2, MS2048, 2048);
        k_gemm16<EPI_BF16_RESBF16><<<dim3(105, 4, 2), 256, 0, stream>>>(
            H2, H2, 99, 0, MS2048, 2048,
            w216, (size_t)512 * 2048, wzp, 2048,
            b2, 512,
            O116_2, nullptr, 8, MS512,
            Ob2, MS512, 512);
        // ---- LN2 + pair sum -> output ----
        k_ln2pair<<<3360, 256, 0, stream>>>(Ob2, g2, be2, pr ? outv : outt,
                                            pr ? 0 : 1, pr ? 2 : 3);
    }
}